// Round 1
// baseline (1429.869 us; speedup 1.0000x reference)
//
#include <hip/hip_runtime.h>
#include <math.h>

#define C 32
#define C2 1024
#define TM 128
#define TN 128
#define KB 32

// ---------------- Kernel 1: per-atom l2 = y^T S y -> H0 [n, 1024] ----------------
// grid.x = n_atoms, block = 256
__global__ __launch_bounds__(256) void k_l2(const float* __restrict__ x,
                                            const int* __restrict__ idx,
                                            const float* __restrict__ S,
                                            float* __restrict__ H0,
                                            int d) {
    __shared__ float sS[18 * 18];
    __shared__ float sy[18][C];
    __shared__ float sSy[18][C];
    int a = blockIdx.x;
    int tid = threadIdx.x;
    int dd = d * d;
    for (int i = tid; i < dd; i += 256) sS[i] = S[i];
    int rows = d * C;
    for (int i = tid; i < rows; i += 256) {
        int bi = i >> 5, c = i & 31;
        int r = idx[a * d + bi];
        sy[bi][c] = x[(size_t)r * C + c];
    }
    __syncthreads();
    // Sy[i][m] = sum_j S[i][j] * y[j][m]
    for (int i = tid; i < rows; i += 256) {
        int bi = i >> 5, m = i & 31;
        float acc = 0.f;
        for (int j = 0; j < d; ++j) acc += sS[bi * d + j] * sy[j][m];
        sSy[bi][m] = acc;
    }
    __syncthreads();
    // l2[c][m] = sum_i y[i][c] * Sy[i][m]
    float* out = H0 + (size_t)a * C2;
    for (int o = tid; o < C2; o += 256) {
        int c = o >> 5, m = o & 31;
        float acc = 0.f;
        for (int i = 0; i < d; ++i) acc += sy[i][c] * sSy[i][m];
        out[o] = acc;
    }
}

// ---------------- Kernel 2/4: C = [silu](A @ W^T + b) ----------------
// A: [M, 1024], W: [1024, 1024] row-major (output-feature major), C: [M, 1024]
// grid = (M/128, 8), block = 256 (16x16 threads, 8x8 micro-tile)
template <int DO_SILU>
__global__ __launch_bounds__(256) void k_gemm(const float* __restrict__ A,
                                              const float* __restrict__ W,
                                              const float* __restrict__ bias,
                                              float* __restrict__ Cmat) {
    __shared__ float As[KB][TM + 4];
    __shared__ float Bs[KB][TN + 4];
    int bm = blockIdx.x, bn = blockIdx.y;
    int tid = threadIdx.x;
    int tx = tid & 15, ty = tid >> 4;
    float acc[8][8];
#pragma unroll
    for (int i = 0; i < 8; ++i)
#pragma unroll
        for (int j = 0; j < 8; ++j) acc[i][j] = 0.f;

    const float* Ablk = A + (size_t)bm * TM * C2;
    const float* Wblk = W + (size_t)bn * TN * C2;

    for (int k0 = 0; k0 < C2; k0 += KB) {
#pragma unroll
        for (int l = 0; l < 4; ++l) {
            int s = tid + l * 256;           // 0..1023
            int row = s >> 3;                // 0..127
            int k4 = (s & 7) << 2;           // 0,4,...,28
            float4 va = *(const float4*)(Ablk + (size_t)row * C2 + k0 + k4);
            As[k4 + 0][row] = va.x; As[k4 + 1][row] = va.y;
            As[k4 + 2][row] = va.z; As[k4 + 3][row] = va.w;
            float4 vb = *(const float4*)(Wblk + (size_t)row * C2 + k0 + k4);
            Bs[k4 + 0][row] = vb.x; Bs[k4 + 1][row] = vb.y;
            Bs[k4 + 2][row] = vb.z; Bs[k4 + 3][row] = vb.w;
        }
        __syncthreads();
#pragma unroll
        for (int kk = 0; kk < KB; ++kk) {
            float a0[8], b0[8];
            *(float4*)&a0[0] = *(const float4*)&As[kk][ty * 8];
            *(float4*)&a0[4] = *(const float4*)&As[kk][ty * 8 + 4];
            *(float4*)&b0[0] = *(const float4*)&Bs[kk][tx * 8];
            *(float4*)&b0[4] = *(const float4*)&Bs[kk][tx * 8 + 4];
#pragma unroll
            for (int i = 0; i < 8; ++i)
#pragma unroll
                for (int j = 0; j < 8; ++j)
                    acc[i][j] = fmaf(a0[i], b0[j], acc[i][j]);
        }
        __syncthreads();
    }
    // epilogue
#pragma unroll
    for (int i = 0; i < 8; ++i) {
        int m = bm * TM + ty * 8 + i;
#pragma unroll
        for (int j0 = 0; j0 < 8; j0 += 4) {
            int n = bn * TN + tx * 8 + j0;
            float4 v;
            float* pv = &v.x;
#pragma unroll
            for (int j = 0; j < 4; ++j) {
                float val = acc[i][j0 + j] + bias[n + j];
                if (DO_SILU) val = val / (1.f + __expf(-val));
                pv[j] = val;
            }
            *(float4*)&Cmat[(size_t)m * C2 + n] = v;
        }
    }
}

// ---------------- Kernel 3: LayerNorm over 1024, in place ----------------
// grid = n_atoms, block = 256 (4 floats/thread)
__global__ __launch_bounds__(256) void k_ln(float* __restrict__ H,
                                            const float* __restrict__ g,
                                            const float* __restrict__ beta) {
    int a = blockIdx.x, tid = threadIdx.x;
    float* row = H + (size_t)a * C2;
    float4 v = *(const float4*)&row[tid * 4];
    float s = v.x + v.y + v.z + v.w;
    float s2 = v.x * v.x + v.y * v.y + v.z * v.z + v.w * v.w;
#pragma unroll
    for (int off = 32; off > 0; off >>= 1) {
        s += __shfl_down(s, off);
        s2 += __shfl_down(s2, off);
    }
    __shared__ float red[8];
    int wid = tid >> 6;
    if ((tid & 63) == 0) { red[wid] = s; red[4 + wid] = s2; }
    __syncthreads();
    float tot = red[0] + red[1] + red[2] + red[3];
    float tot2 = red[4] + red[5] + red[6] + red[7];
    float mean = tot * (1.f / 1024.f);
    float var = tot2 * (1.f / 1024.f) - mean * mean;
    float rstd = rsqrtf(var + 1e-5f);
    float4 gv = *(const float4*)&g[tid * 4];
    float4 bv = *(const float4*)&beta[tid * 4];
    v.x = (v.x - mean) * rstd * gv.x + bv.x;
    v.y = (v.y - mean) * rstd * gv.y + bv.y;
    v.z = (v.z - mean) * rstd * gv.z + bv.z;
    v.w = (v.w - mean) * rstd * gv.w + bv.w;
    *(float4*)&row[tid * 4] = v;
}

// ---------------- Kernel 5: out = y @ l2' per atom, scatter ----------------
// grid = n_atoms, block = 256
__global__ __launch_bounds__(256) void k_out(const float* __restrict__ x,
                                             const int* __restrict__ idx,
                                             const float* __restrict__ L,
                                             float* __restrict__ out,
                                             int d) {
    __shared__ float sL[C2];
    __shared__ float sy[18][C];
    int a = blockIdx.x;
    int tid = threadIdx.x;
    const float* Lr = L + (size_t)a * C2;
    for (int i = tid; i < C2; i += 256) sL[i] = Lr[i];
    int rows = d * C;
    for (int i = tid; i < rows; i += 256) {
        int bi = i >> 5, c = i & 31;
        int r = idx[a * d + bi];
        sy[bi][c] = x[(size_t)r * C + c];
    }
    __syncthreads();
    for (int o = tid; o < rows; o += 256) {
        int bi = o >> 5, m = o & 31;
        float acc = 0.f;
#pragma unroll
        for (int c = 0; c < C; ++c) acc += sy[bi][c] * sL[c * C + m];
        int r = idx[a * d + bi];
        out[(size_t)r * C + m] = acc;
    }
}

extern "C" void kernel_launch(void* const* d_in, const int* in_sizes, int n_in,
                              void* d_out, int out_size, void* d_ws, size_t ws_size,
                              hipStream_t stream) {
    const float* x = (const float*)d_in[0];
    static const int DIMS[3] = {8, 14, 18};
    static const int NATOMS[3] = {8192, 8192, 4096};

    float* ws0 = (float*)d_ws;                    // up to 8192*1024 floats (32 MB)
    float* ws1 = ws0 + (size_t)8192 * C2;         // another 32 MB

    for (int t = 0; t < 3; ++t) {
        const int* idx = (const int*)d_in[1 + 8 * t];
        const float* S = (const float*)d_in[2 + 8 * t];
        const float* W1 = (const float*)d_in[3 + 8 * t];
        const float* b1 = (const float*)d_in[4 + 8 * t];
        const float* g = (const float*)d_in[5 + 8 * t];
        const float* be = (const float*)d_in[6 + 8 * t];
        const float* W2 = (const float*)d_in[7 + 8 * t];
        const float* b2 = (const float*)d_in[8 + 8 * t];
        int n = NATOMS[t], d = DIMS[t];

        k_l2<<<n, 256, 0, stream>>>(x, idx, S, ws0, d);
        dim3 g1(n / TM, C2 / TN);
        k_gemm<1><<<g1, 256, 0, stream>>>(ws0, W1, b1, ws1);
        k_ln<<<n, 256, 0, stream>>>(ws1, g, be);
        k_gemm<0><<<g1, 256, 0, stream>>>(ws1, W2, b2, ws0);
        k_out<<<n, 256, 0, stream>>>(x, idx, ws0, (float*)d_out, d);
    }
}

// Round 6
// 643.109 us; speedup vs baseline: 2.2234x; 2.2234x over previous
//
#include <hip/hip_runtime.h>
#include <math.h>

#define C 32
#define C2 1024

typedef float f32x4 __attribute__((ext_vector_type(4)));
typedef short s16x8 __attribute__((ext_vector_type(8)));

// ---- bf16 helpers (RNE, manual) ----
__device__ __forceinline__ unsigned short f2bf(float f) {
    unsigned u = __builtin_bit_cast(unsigned, f);
    u = (u + 0x7fffu + ((u >> 16) & 1u)) >> 16;
    return (unsigned short)u;
}
__device__ __forceinline__ float bf2f(unsigned short b) {
    unsigned u = ((unsigned)b) << 16;
    return __builtin_bit_cast(float, u);
}

__device__ __forceinline__ void gload16(const void* g, void* l) {
    __builtin_amdgcn_global_load_lds((const __attribute__((address_space(1))) void*)g,
                                     (__attribute__((address_space(3))) void*)l,
                                     16, 0, 0);
}

// ---------------- W -> (hi, lo) bf16 split. 1M elems, grid=1024 ----------------
__global__ __launch_bounds__(256) void k_conv(const float* __restrict__ src,
                                              unsigned short* __restrict__ hi,
                                              unsigned short* __restrict__ lo) {
    int i = (blockIdx.x * 256 + threadIdx.x) * 4;
    float4 v = *(const float4*)(src + i);
    ushort4 h, l;
    h.x = f2bf(v.x); l.x = f2bf(v.x - bf2f(h.x));
    h.y = f2bf(v.y); l.y = f2bf(v.y - bf2f(h.y));
    h.z = f2bf(v.z); l.z = f2bf(v.z - bf2f(h.z));
    h.w = f2bf(v.w); l.w = f2bf(v.w - bf2f(h.w));
    *(ushort4*)(hi + i) = h;
    *(ushort4*)(lo + i) = l;
}

// ---------------- per-atom l2 = y^T S y -> (Ahi, Alo) bf16 ----------------
__global__ __launch_bounds__(256) void k_l2(const float* __restrict__ x,
                                            const int* __restrict__ idx,
                                            const float* __restrict__ S,
                                            unsigned short* __restrict__ Ahi,
                                            unsigned short* __restrict__ Alo,
                                            int d) {
    __shared__ float sS[18 * 18];
    __shared__ float sy[18][C];
    __shared__ float sSy[18][C];
    int a = blockIdx.x;
    int tid = threadIdx.x;
    int dd = d * d;
    for (int i = tid; i < dd; i += 256) sS[i] = S[i];
    int rows = d * C;
    for (int i = tid; i < rows; i += 256) {
        int bi = i >> 5, c = i & 31;
        int r = idx[a * d + bi];
        sy[bi][c] = x[(size_t)r * C + c];
    }
    __syncthreads();
    for (int i = tid; i < rows; i += 256) {
        int bi = i >> 5, m = i & 31;
        float acc = 0.f;
        for (int j = 0; j < d; ++j) acc += sS[bi * d + j] * sy[j][m];
        sSy[bi][m] = acc;
    }
    __syncthreads();
    for (int o = tid; o < C2; o += 256) {
        int c = o >> 5, m = o & 31;
        float acc = 0.f;
        for (int i = 0; i < d; ++i) acc += sy[i][c] * sSy[i][m];
        unsigned short h = f2bf(acc);
        Ahi[(size_t)a * C2 + o] = h;
        Alo[(size_t)a * C2 + o] = f2bf(acc - bf2f(h));
    }
}

// ---------------- MFMA GEMM: Out = [silu](A @ W^T + b), bf16x3 split ----------------
// tile 128x128, BK=32, 256 threads = 4 waves, each 64x64 (4x4 frags 16x16x32)
// LDS linear (global_load_lds); k-slot XOR swizzle applied on BOTH global source
// and ds_read (rule #21): slot ^= (row>>1)&3
template <int DO_SILU>
__global__ __launch_bounds__(256) void k_gemm_mfma(const unsigned short* __restrict__ Ahi,
                                                   const unsigned short* __restrict__ Alo,
                                                   const unsigned short* __restrict__ Whi,
                                                   const unsigned short* __restrict__ Wlo,
                                                   const float* __restrict__ bias,
                                                   float* __restrict__ Out) {
    __shared__ short lds[16384];  // 32 KB
    short* As_h = lds;
    short* As_l = lds + 4096;
    short* Ws_h = lds + 8192;
    short* Ws_l = lds + 12288;

    const int tid = threadIdx.x;
    const int wid = tid >> 6, lane = tid & 63;
    const int bm = blockIdx.x, bn = blockIdx.y;
    const int wr = wid >> 1, wc = wid & 1;

    size_t gA[2], gW[2];
    int ldsoff[2];
#pragma unroll
    for (int it = 0; it < 2; ++it) {
        int L = wid * 128 + it * 64 + lane;   // 16B-chunk index, 0..511
        int row = L >> 2, slot = L & 3;
        int sw = slot ^ ((row >> 1) & 3);
        gA[it] = (size_t)(bm * 128 + row) * C2 + sw * 8;
        gW[it] = (size_t)(bn * 128 + row) * C2 + sw * 8;
        ldsoff[it] = wid * 1024 + it * 512;   // shorts (wave-uniform base)
    }

    const int col = lane & 15, g = lane >> 4;
    int aoffs[4], woffs[4];
#pragma unroll
    for (int i = 0; i < 4; ++i) {
        int ra = wr * 64 + i * 16 + col;
        aoffs[i] = ra * 32 + (g ^ ((ra >> 1) & 3)) * 8;
        int rw = wc * 64 + i * 16 + col;
        woffs[i] = rw * 32 + (g ^ ((rw >> 1) & 3)) * 8;
    }

    f32x4 acc[4][4] = {};

    for (int k0 = 0; k0 < C2; k0 += 32) {
#pragma unroll
        for (int it = 0; it < 2; ++it) {
            gload16(Ahi + gA[it] + k0, As_h + ldsoff[it]);
            gload16(Alo + gA[it] + k0, As_l + ldsoff[it]);
            gload16(Whi + gW[it] + k0, Ws_h + ldsoff[it]);
            gload16(Wlo + gW[it] + k0, Ws_l + ldsoff[it]);
        }
        __syncthreads();
        s16x8 ah[4], al[4], wh[4], wl[4];
#pragma unroll
        for (int i = 0; i < 4; ++i) {
            ah[i] = *(const s16x8*)(As_h + aoffs[i]);
            al[i] = *(const s16x8*)(As_l + aoffs[i]);
            wh[i] = *(const s16x8*)(Ws_h + woffs[i]);
            wl[i] = *(const s16x8*)(Ws_l + woffs[i]);
        }
#pragma unroll
        for (int mi = 0; mi < 4; ++mi)
#pragma unroll
            for (int ni = 0; ni < 4; ++ni) {
                acc[mi][ni] = __builtin_amdgcn_mfma_f32_16x16x32_bf16(ah[mi], wh[ni], acc[mi][ni], 0, 0, 0);
                acc[mi][ni] = __builtin_amdgcn_mfma_f32_16x16x32_bf16(ah[mi], wl[ni], acc[mi][ni], 0, 0, 0);
                acc[mi][ni] = __builtin_amdgcn_mfma_f32_16x16x32_bf16(al[mi], wh[ni], acc[mi][ni], 0, 0, 0);
            }
        __syncthreads();
    }

    float bv[4];
#pragma unroll
    for (int ni = 0; ni < 4; ++ni) bv[ni] = bias[bn * 128 + wc * 64 + ni * 16 + col];
#pragma unroll
    for (int mi = 0; mi < 4; ++mi)
#pragma unroll
        for (int ni = 0; ni < 4; ++ni) {
            int n = bn * 128 + wc * 64 + ni * 16 + col;
#pragma unroll
            for (int r = 0; r < 4; ++r) {
                int m = bm * 128 + wr * 64 + mi * 16 + g * 4 + r;
                float v = acc[mi][ni][r] + bv[ni];
                if (DO_SILU) v = v / (1.f + __expf(-v));
                Out[(size_t)m * C2 + n] = v;
            }
        }
}

// ---------------- LayerNorm over 1024 -> (Bhi, Blo) bf16 ----------------
__global__ __launch_bounds__(256) void k_ln(const float* __restrict__ H,
                                            const float* __restrict__ g,
                                            const float* __restrict__ beta,
                                            unsigned short* __restrict__ Bhi,
                                            unsigned short* __restrict__ Blo) {
    int a = blockIdx.x, tid = threadIdx.x;
    const float* row = H + (size_t)a * C2;
    float4 v = *(const float4*)&row[tid * 4];
    float s = v.x + v.y + v.z + v.w;
    float s2 = v.x * v.x + v.y * v.y + v.z * v.z + v.w * v.w;
#pragma unroll
    for (int off = 32; off > 0; off >>= 1) {
        s += __shfl_down(s, off);
        s2 += __shfl_down(s2, off);
    }
    __shared__ float red[8];
    int wid = tid >> 6;
    if ((tid & 63) == 0) { red[wid] = s; red[4 + wid] = s2; }
    __syncthreads();
    float tot = red[0] + red[1] + red[2] + red[3];
    float tot2 = red[4] + red[5] + red[6] + red[7];
    float mean = tot * (1.f / 1024.f);
    float var = tot2 * (1.f / 1024.f) - mean * mean;
    float rstd = rsqrtf(var + 1e-5f);
    float4 gv = *(const float4*)&g[tid * 4];
    float4 bv = *(const float4*)&beta[tid * 4];
    float4 o;
    o.x = (v.x - mean) * rstd * gv.x + bv.x;
    o.y = (v.y - mean) * rstd * gv.y + bv.y;
    o.z = (v.z - mean) * rstd * gv.z + bv.z;
    o.w = (v.w - mean) * rstd * gv.w + bv.w;
    ushort4 h, l;
    h.x = f2bf(o.x); l.x = f2bf(o.x - bf2f(h.x));
    h.y = f2bf(o.y); l.y = f2bf(o.y - bf2f(h.y));
    h.z = f2bf(o.z); l.z = f2bf(o.z - bf2f(h.z));
    h.w = f2bf(o.w); l.w = f2bf(o.w - bf2f(h.w));
    *(ushort4*)(Bhi + (size_t)a * C2 + tid * 4) = h;
    *(ushort4*)(Blo + (size_t)a * C2 + tid * 4) = l;
}

// ---------------- out = y @ l2' per atom, scatter ----------------
__global__ __launch_bounds__(256) void k_out(const float* __restrict__ x,
                                             const int* __restrict__ idx,
                                             const float* __restrict__ L,
                                             float* __restrict__ out,
                                             int d) {
    __shared__ float sL[C2];
    __shared__ float sy[18][C];
    int a = blockIdx.x;
    int tid = threadIdx.x;
    const float* Lr = L + (size_t)a * C2;
    for (int i = tid; i < C2; i += 256) sL[i] = Lr[i];
    int rows = d * C;
    for (int i = tid; i < rows; i += 256) {
        int bi = i >> 5, c = i & 31;
        int r = idx[a * d + bi];
        sy[bi][c] = x[(size_t)r * C + c];
    }
    __syncthreads();
    for (int o = tid; o < rows; o += 256) {
        int bi = o >> 5, m = o & 31;
        float acc = 0.f;
#pragma unroll
        for (int c = 0; c < C; ++c) acc += sy[bi][c] * sL[c * C + m];
        int r = idx[a * d + bi];
        out[(size_t)r * C + m] = acc;
    }
}

extern "C" void kernel_launch(void* const* d_in, const int* in_sizes, int n_in,
                              void* d_out, int out_size, void* d_ws, size_t ws_size,
                              hipStream_t stream) {
    const float* x = (const float*)d_in[0];
    static const int DIMS[3] = {8, 14, 18};
    static const int NATOMS[3] = {8192, 8192, 4096};

    const size_t MB = 1ull << 20;
    char* p = (char*)d_ws;
    unsigned short* w1h = (unsigned short*)(p);
    unsigned short* w1l = (unsigned short*)(p + 2 * MB);
    unsigned short* w2h = (unsigned short*)(p + 4 * MB);
    unsigned short* w2l = (unsigned short*)(p + 6 * MB);
    char* dyn = p + 8 * MB;  // Ahi | Alo | H, each cm*C2 elems

    for (int t = 0; t < 3; ++t) {
        const int* idx = (const int*)d_in[1 + 8 * t];
        const float* S = (const float*)d_in[2 + 8 * t];
        const float* W1 = (const float*)d_in[3 + 8 * t];
        const float* b1 = (const float*)d_in[4 + 8 * t];
        const float* g = (const float*)d_in[5 + 8 * t];
        const float* be = (const float*)d_in[6 + 8 * t];
        const float* W2 = (const float*)d_in[7 + 8 * t];
        const float* b2 = (const float*)d_in[8 + 8 * t];
        int n = NATOMS[t], d = DIMS[t];

        // adaptive chunking: fit 8MB weights + n*(2+2+4)KB/atom in ws_size
        size_t fullneed = 8 * MB + (size_t)n * 8192;
        int nch = (ws_size >= fullneed) ? 1 : 2;
        int cm = n / nch;

        unsigned short* Ahi = (unsigned short*)dyn;
        unsigned short* Alo = (unsigned short*)(dyn + (size_t)cm * 2048);
        float* Hbuf = (float*)(dyn + (size_t)cm * 4096);

        k_conv<<<1024, 256, 0, stream>>>(W1, w1h, w1l);
        k_conv<<<1024, 256, 0, stream>>>(W2, w2h, w2l);

        for (int ch = 0; ch < nch; ++ch) {
            int a0 = ch * cm;
            const int* idxc = idx + (size_t)a0 * d;
            k_l2<<<cm, 256, 0, stream>>>(x, idxc, S, Ahi, Alo, d);
            dim3 gg(cm / 128, 8);
            k_gemm_mfma<1><<<gg, 256, 0, stream>>>(Ahi, Alo, w1h, w1l, b1, Hbuf);
            k_ln<<<cm, 256, 0, stream>>>(Hbuf, g, be, Ahi, Alo);
            k_gemm_mfma<0><<<gg, 256, 0, stream>>>(Ahi, Alo, w2h, w2l, b2, Hbuf);
            k_out<<<cm, 256, 0, stream>>>(x, idxc, Hbuf, (float*)d_out, d);
        }
    }
}

// Round 12
// 515.037 us; speedup vs baseline: 2.7762x; 1.2487x over previous
//
#include <hip/hip_runtime.h>
#include <math.h>

#define C2 1024

typedef float f32x4 __attribute__((ext_vector_type(4)));
typedef short s16x8 __attribute__((ext_vector_type(8)));
typedef unsigned short u16x8 __attribute__((ext_vector_type(8)));

// ---- bf16 helpers (RNE, manual) ----
__device__ __forceinline__ unsigned short f2bf(float f) {
    unsigned u = __builtin_bit_cast(unsigned, f);
    u = (u + 0x7fffu + ((u >> 16) & 1u)) >> 16;
    return (unsigned short)u;
}
__device__ __forceinline__ float bf2f(unsigned short b) {
    unsigned u = ((unsigned)b) << 16;
    return __builtin_bit_cast(float, u);
}

__device__ __forceinline__ void gload16(const void* g, void* l) {
    __builtin_amdgcn_global_load_lds((const __attribute__((address_space(1))) void*)g,
                                     (__attribute__((address_space(3))) void*)l,
                                     16, 0, 0);
}

// type resolve helpers: t from (pos, s1, s2); start of that type's range
__device__ __forceinline__ int type_of(int pos, int s1, int s2) {
    return (pos >= s2) ? 2 : (pos >= s1) ? 1 : 0;
}
__device__ __forceinline__ int dim_of(int t) { return (t == 0) ? 8 : (t == 1) ? 14 : 18; }

// ---------------- conv: up to 6 fp32 1M-elem matrices -> (hi,lo) bf16 pairs ----------------
// grid = nmat*1024; w layout: per mat 2M shorts: [hi 1M | lo 1M]
__global__ __launch_bounds__(256) void k_conv(const float* __restrict__ s0, const float* __restrict__ s1,
                                              const float* __restrict__ s2, const float* __restrict__ s3,
                                              const float* __restrict__ s4, const float* __restrict__ s5,
                                              unsigned short* __restrict__ w) {
    int mat = blockIdx.x >> 10, bb = blockIdx.x & 1023;
    const float* src = (mat == 0) ? s0 : (mat == 1) ? s1 : (mat == 2) ? s2
                       : (mat == 3) ? s3 : (mat == 4) ? s4 : s5;
    int i = (bb * 256 + threadIdx.x) * 4;
    unsigned short* hi = w + (size_t)mat * 2097152;
    unsigned short* lo = hi + 1048576;
    float4 v = *(const float4*)(src + i);
    ushort4 h, l;
    h.x = f2bf(v.x); l.x = f2bf(v.x - bf2f(h.x));
    h.y = f2bf(v.y); l.y = f2bf(v.y - bf2f(h.y));
    h.z = f2bf(v.z); l.z = f2bf(v.z - bf2f(h.z));
    h.w = f2bf(v.w); l.w = f2bf(v.w - bf2f(h.w));
    *(ushort4*)(hi + i) = h;
    *(ushort4*)(lo + i) = l;
}

// ---------------- l2 = y^T S y -> (Ahi,Alo) bf16 pair. wave-per-atom, 4 atoms/block ----------------
__global__ __launch_bounds__(256) void k_l2(const float* __restrict__ x,
                                            const int* __restrict__ i0, const int* __restrict__ i1,
                                            const int* __restrict__ i2,
                                            const float* __restrict__ S0, const float* __restrict__ S1,
                                            const float* __restrict__ S2,
                                            unsigned short* __restrict__ Ahi, unsigned short* __restrict__ Alo,
                                            int s1, int s2) {
    __shared__ float sS[324];
    __shared__ float sy[4][18][32];
    __shared__ float sSy[4][18][32];
    const int tid = threadIdx.x, g = tid >> 6, lane = tid & 63;
    const int a0 = blockIdx.x * 4;
    const int t = type_of(a0, s1, s2);
    const int d = dim_of(t);
    const int* idx = (t == 0) ? i0 : (t == 1) ? i1 : i2;
    const float* S = (t == 0) ? S0 : (t == 1) ? S1 : S2;
    const int start = (t == 0) ? 0 : (t == 1) ? s1 : s2;
    const int dd = d * d;
    for (int i = tid; i < dd; i += 256) sS[i] = S[i];
    const int a = a0 + g, la = a - start;
    const int nf4 = d * 8;
    for (int k = lane; k < nf4; k += 64) {
        int bi = k >> 3, f4 = (k & 7) * 4;
        int r = idx[la * d + bi];
        *(float4*)&sy[g][bi][f4] = *(const float4*)(x + (size_t)r * 32 + f4);
    }
    __syncthreads();
    for (int k = lane; k < d * 32; k += 64) {
        int i = k >> 5, m = k & 31;
        float acc = 0.f;
        for (int j = 0; j < d; ++j) acc += sS[i * d + j] * sy[g][j][m];
        sSy[g][i][m] = acc;
    }
    __syncthreads();
    const int c = lane >> 1, mb = (lane & 1) * 16;
    float acc[16];
#pragma unroll
    for (int mm = 0; mm < 16; ++mm) acc[mm] = 0.f;
    for (int i = 0; i < d; ++i) {
        float yc = sy[g][i][c];
#pragma unroll
        for (int mm = 0; mm < 16; ++mm) acc[mm] += yc * sSy[g][i][mb + mm];
    }
    u16x8 h0, h1, l0, l1;
#pragma unroll
    for (int mm = 0; mm < 8; ++mm) {
        unsigned short h = f2bf(acc[mm]); h0[mm] = h; l0[mm] = f2bf(acc[mm] - bf2f(h));
    }
#pragma unroll
    for (int mm = 0; mm < 8; ++mm) {
        unsigned short h = f2bf(acc[8 + mm]); h1[mm] = h; l1[mm] = f2bf(acc[8 + mm] - bf2f(h));
    }
    size_t off = (size_t)a * C2 + lane * 16;
    *(u16x8*)(Ahi + off) = h0; *(u16x8*)(Ahi + off + 8) = h1;
    *(u16x8*)(Alo + off) = l0; *(u16x8*)(Alo + off + 8) = l1;
}

// ---------------- MFMA GEMM (proven round-6 core) + per-M-tile type W select ----------------
template <int DO_SILU>
__global__ __launch_bounds__(256) void k_gemm_mfma(const unsigned short* __restrict__ Ahi,
                                                   const unsigned short* __restrict__ Alo,
                                                   const unsigned short* __restrict__ W0h, const unsigned short* __restrict__ W0l,
                                                   const unsigned short* __restrict__ W1h, const unsigned short* __restrict__ W1l,
                                                   const unsigned short* __restrict__ W2h, const unsigned short* __restrict__ W2l,
                                                   const float* __restrict__ bias0, const float* __restrict__ bias1,
                                                   const float* __restrict__ bias2,
                                                   float* __restrict__ Out, int tb1, int tb2) {
    __shared__ short lds[16384];
    short* As_h = lds;
    short* As_l = lds + 4096;
    short* Ws_h = lds + 8192;
    short* Ws_l = lds + 12288;

    const int tid = threadIdx.x;
    const int wid = tid >> 6, lane = tid & 63;
    const int bm = blockIdx.x, bn = blockIdx.y;
    const int wr = wid >> 1, wc = wid & 1;

    const unsigned short* Whi; const unsigned short* Wlo; const float* bias;
    if (bm >= tb2)      { Whi = W2h; Wlo = W2l; bias = bias2; }
    else if (bm >= tb1) { Whi = W1h; Wlo = W1l; bias = bias1; }
    else                { Whi = W0h; Wlo = W0l; bias = bias0; }

    size_t gA[2], gW[2];
    int ldsoff[2];
#pragma unroll
    for (int it = 0; it < 2; ++it) {
        int L = wid * 128 + it * 64 + lane;   // 16B-chunk index, 0..511
        int row = L >> 2, slot = L & 3;
        int sw = slot ^ ((row >> 1) & 3);
        gA[it] = (size_t)(bm * 128 + row) * C2 + sw * 8;
        gW[it] = (size_t)(bn * 128 + row) * C2 + sw * 8;
        ldsoff[it] = wid * 1024 + it * 512;
    }

    const int col = lane & 15, g = lane >> 4;
    int aoffs[4], woffs[4];
#pragma unroll
    for (int i = 0; i < 4; ++i) {
        int ra = wr * 64 + i * 16 + col;
        aoffs[i] = ra * 32 + (g ^ ((ra >> 1) & 3)) * 8;
        int rw = wc * 64 + i * 16 + col;
        woffs[i] = rw * 32 + (g ^ ((rw >> 1) & 3)) * 8;
    }

    f32x4 acc[4][4] = {};

    for (int k0 = 0; k0 < C2; k0 += 32) {
#pragma unroll
        for (int it = 0; it < 2; ++it) {
            gload16(Ahi + gA[it] + k0, As_h + ldsoff[it]);
            gload16(Alo + gA[it] + k0, As_l + ldsoff[it]);
            gload16(Whi + gW[it] + k0, Ws_h + ldsoff[it]);
            gload16(Wlo + gW[it] + k0, Ws_l + ldsoff[it]);
        }
        __syncthreads();
        s16x8 ah[4], al[4], wh[4], wl[4];
#pragma unroll
        for (int i = 0; i < 4; ++i) {
            ah[i] = *(const s16x8*)(As_h + aoffs[i]);
            al[i] = *(const s16x8*)(As_l + aoffs[i]);
            wh[i] = *(const s16x8*)(Ws_h + woffs[i]);
            wl[i] = *(const s16x8*)(Ws_l + woffs[i]);
        }
#pragma unroll
        for (int mi = 0; mi < 4; ++mi)
#pragma unroll
            for (int ni = 0; ni < 4; ++ni) {
                acc[mi][ni] = __builtin_amdgcn_mfma_f32_16x16x32_bf16(ah[mi], wh[ni], acc[mi][ni], 0, 0, 0);
                acc[mi][ni] = __builtin_amdgcn_mfma_f32_16x16x32_bf16(ah[mi], wl[ni], acc[mi][ni], 0, 0, 0);
                acc[mi][ni] = __builtin_amdgcn_mfma_f32_16x16x32_bf16(al[mi], wh[ni], acc[mi][ni], 0, 0, 0);
            }
        __syncthreads();
    }

    float bv[4];
#pragma unroll
    for (int ni = 0; ni < 4; ++ni) bv[ni] = bias[bn * 128 + wc * 64 + ni * 16 + col];
#pragma unroll
    for (int mi = 0; mi < 4; ++mi)
#pragma unroll
        for (int ni = 0; ni < 4; ++ni) {
            int n = bn * 128 + wc * 64 + ni * 16 + col;
#pragma unroll
            for (int r = 0; r < 4; ++r) {
                int m = bm * 128 + wr * 64 + mi * 16 + g * 4 + r;
                float v = acc[mi][ni][r] + bv[ni];
                if (DO_SILU) v = v / (1.f + __expf(-v));
                Out[(size_t)m * C2 + n] = v;
            }
        }
}

// ---------------- LayerNorm: wave-per-row, 4 rows/block, no barriers ----------------
__global__ __launch_bounds__(256) void k_ln(const float* __restrict__ H,
                                            const float* __restrict__ g0, const float* __restrict__ g1,
                                            const float* __restrict__ g2,
                                            const float* __restrict__ b0, const float* __restrict__ b1,
                                            const float* __restrict__ b2,
                                            unsigned short* __restrict__ Bhi, unsigned short* __restrict__ Blo,
                                            int s1, int s2) {
    const int tid = threadIdx.x, w = tid >> 6, lane = tid & 63;
    const int row = blockIdx.x * 4 + w;
    const int t = type_of(row, s1, s2);
    const float* gg = (t == 0) ? g0 : (t == 1) ? g1 : g2;
    const float* bb = (t == 0) ? b0 : (t == 1) ? b1 : b2;
    const float* rp = H + (size_t)row * C2;
    float4 v[4];
    float s = 0.f, s2v = 0.f;
#pragma unroll
    for (int k = 0; k < 4; ++k) {
        v[k] = *(const float4*)(rp + k * 256 + lane * 4);
        s += v[k].x + v[k].y + v[k].z + v[k].w;
        s2v += v[k].x * v[k].x + v[k].y * v[k].y + v[k].z * v[k].z + v[k].w * v[k].w;
    }
#pragma unroll
    for (int off = 1; off < 64; off <<= 1) {
        s += __shfl_xor(s, off);
        s2v += __shfl_xor(s2v, off);
    }
    float mean = s * (1.f / 1024.f);
    float var = s2v * (1.f / 1024.f) - mean * mean;
    float rstd = rsqrtf(var + 1e-5f);
#pragma unroll
    for (int k = 0; k < 4; ++k) {
        float4 gv = *(const float4*)(gg + k * 256 + lane * 4);
        float4 bv = *(const float4*)(bb + k * 256 + lane * 4);
        float o0 = (v[k].x - mean) * rstd * gv.x + bv.x;
        float o1 = (v[k].y - mean) * rstd * gv.y + bv.y;
        float o2 = (v[k].z - mean) * rstd * gv.z + bv.z;
        float o3 = (v[k].w - mean) * rstd * gv.w + bv.w;
        ushort4 h, l;
        h.x = f2bf(o0); l.x = f2bf(o0 - bf2f(h.x));
        h.y = f2bf(o1); l.y = f2bf(o1 - bf2f(h.y));
        h.z = f2bf(o2); l.z = f2bf(o2 - bf2f(h.z));
        h.w = f2bf(o3); l.w = f2bf(o3 - bf2f(h.w));
        size_t off2 = (size_t)row * C2 + k * 256 + lane * 4;
        *(ushort4*)(Bhi + off2) = h;
        *(ushort4*)(Blo + off2) = l;
    }
}

// ---------------- out = y @ l2' scatter. wave-per-atom, 4 atoms/block ----------------
__global__ __launch_bounds__(256) void k_out(const float* __restrict__ x,
                                             const int* __restrict__ i0, const int* __restrict__ i1,
                                             const int* __restrict__ i2,
                                             const float* __restrict__ L,
                                             float* __restrict__ out, int s1, int s2) {
    __shared__ float sL[4][C2];
    __shared__ float sy[4][18][32];
    const int tid = threadIdx.x, g = tid >> 6, lane = tid & 63;
    const int a0 = blockIdx.x * 4;
    const int t = type_of(a0, s1, s2);
    const int d = dim_of(t);
    const int* idx = (t == 0) ? i0 : (t == 1) ? i1 : i2;
    const int start = (t == 0) ? 0 : (t == 1) ? s1 : s2;
    const int a = a0 + g, la = a - start;
    for (int k = lane; k < 256; k += 64)
        *(float4*)&sL[g][k * 4] = *(const float4*)(L + (size_t)a * C2 + k * 4);
    const int nf4 = d * 8;
    for (int k = lane; k < nf4; k += 64) {
        int bi = k >> 3, f4 = (k & 7) * 4;
        int r = idx[la * d + bi];
        *(float4*)&sy[g][bi][f4] = *(const float4*)(x + (size_t)r * 32 + f4);
    }
    __syncthreads();
    for (int k = lane; k < nf4; k += 64) {
        int bi = k >> 3, m4 = (k & 7) * 4;
        float ax = 0.f, ay = 0.f, az = 0.f, aw = 0.f;
#pragma unroll
        for (int c = 0; c < 32; ++c) {
            float yv = sy[g][bi][c];
            float4 lv = *(const float4*)&sL[g][c * 32 + m4];
            ax += yv * lv.x; ay += yv * lv.y; az += yv * lv.z; aw += yv * lv.w;
        }
        int r = idx[la * d + bi];
        float4 o = {ax, ay, az, aw};
        *(float4*)(out + (size_t)r * 32 + m4) = o;
    }
}

extern "C" void kernel_launch(void* const* d_in, const int* in_sizes, int n_in,
                              void* d_out, int out_size, void* d_ws, size_t ws_size,
                              hipStream_t stream) {
    const float* x = (const float*)d_in[0];
    static const int DIMS[3] = {8, 14, 18};
    static const int NATOMS[3] = {8192, 8192, 4096};
    const size_t MiB = 1ull << 20;
    const int BIG = 0x40000000;
    char* p = (char*)d_ws;

    // unpack inputs
    const int* idxs[3]; const float* Ss[3]; const float* W1s[3]; const float* b1s[3];
    const float* gs[3]; const float* bes[3]; const float* W2s[3]; const float* b2s[3];
    for (int t = 0; t < 3; ++t) {
        idxs[t] = (const int*)d_in[1 + 8 * t];
        Ss[t] = (const float*)d_in[2 + 8 * t];
        W1s[t] = (const float*)d_in[3 + 8 * t];
        b1s[t] = (const float*)d_in[4 + 8 * t];
        gs[t] = (const float*)d_in[5 + 8 * t];
        bes[t] = (const float*)d_in[6 + 8 * t];
        W2s[t] = (const float*)d_in[7 + 8 * t];
        b2s[t] = (const float*)d_in[8 + 8 * t];
    }
    float* outp = (float*)d_out;

    if (ws_size >= 184 * MiB) {
        // ---------- grouped path: one dispatch per stage ----------
        unsigned short* w = (unsigned short*)p;                 // 24 MiB: 6 mats x [hi|lo]
        unsigned short* Ahi = (unsigned short*)(p + 24 * MiB);  // 40 MiB
        unsigned short* Alo = (unsigned short*)(p + 64 * MiB);  // 40 MiB
        float* H = (float*)(p + 104 * MiB);                     // 80 MiB (end 184)
        // mats: {t0W1, t0W2, t1W1, t1W2, t2W1, t2W2}
        k_conv<<<6 * 1024, 256, 0, stream>>>(W1s[0], W2s[0], W1s[1], W2s[1], W1s[2], W2s[2], w);
        k_l2<<<5120, 256, 0, stream>>>(x, idxs[0], idxs[1], idxs[2], Ss[0], Ss[1], Ss[2],
                                       Ahi, Alo, 8192, 16384);
        dim3 gg(160, 8);
        k_gemm_mfma<1><<<gg, 256, 0, stream>>>(Ahi, Alo,
            w + 0 * 2097152, w + 0 * 2097152 + 1048576,
            w + 2 * 2097152, w + 2 * 2097152 + 1048576,
            w + 4 * 2097152, w + 4 * 2097152 + 1048576,
            b1s[0], b1s[1], b1s[2], H, 64, 128);
        k_ln<<<5120, 256, 0, stream>>>(H, gs[0], gs[1], gs[2], bes[0], bes[1], bes[2],
                                       Ahi, Alo, 8192, 16384);
        k_gemm_mfma<0><<<gg, 256, 0, stream>>>(Ahi, Alo,
            w + 1 * 2097152, w + 1 * 2097152 + 1048576,
            w + 3 * 2097152, w + 3 * 2097152 + 1048576,
            w + 5 * 2097152, w + 5 * 2097152 + 1048576,
            b2s[0], b2s[1], b2s[2], H, 64, 128);
        k_out<<<5120, 256, 0, stream>>>(x, idxs[0], idxs[1], idxs[2], H, outp, 8192, 16384);
    } else {
        // ---------- per-type fallback (round-6 proven footprint <= 72 MiB) ----------
        unsigned short* wt = (unsigned short*)p;  // 8 MiB: W1 pair + W2 pair
        char* dyn = p + 8 * MiB;
        for (int t = 0; t < 3; ++t) {
            int n = NATOMS[t], d = DIMS[t];
            size_t fullneed = 8 * MiB + (size_t)n * 8192;
            int nch = (ws_size >= fullneed) ? 1 : 2;
            int cm = n / nch;
            unsigned short* Ahi = (unsigned short*)dyn;
            unsigned short* Alo = (unsigned short*)(dyn + (size_t)cm * 2048);
            float* Hbuf = (float*)(dyn + (size_t)cm * 4096);
            // slot/boundary trick: put this type's params in slot t, set s1/s2 so t resolves
            int ss1 = (t == 0) ? BIG : 0;
            int ss2 = (t == 2) ? 0 : BIG;
            k_conv<<<2 * 1024, 256, 0, stream>>>(W1s[t], W2s[t], W1s[t], W1s[t], W1s[t], W1s[t], wt);
            for (int ch = 0; ch < nch; ++ch) {
                const int* idxc = idxs[t] + (size_t)(ch * cm) * d;
                k_l2<<<cm / 4, 256, 0, stream>>>(x, idxc, idxc, idxc, Ss[t], Ss[t], Ss[t],
                                                 Ahi, Alo, ss1, ss2);
                dim3 g1(cm / 128, 8);
                k_gemm_mfma<1><<<g1, 256, 0, stream>>>(Ahi, Alo,
                    wt + 0, wt + 1048576, wt + 0, wt + 1048576, wt + 0, wt + 1048576,
                    b1s[t], b1s[t], b1s[t], Hbuf, BIG, BIG);
                k_ln<<<cm / 4, 256, 0, stream>>>(Hbuf, gs[t], gs[t], gs[t], bes[t], bes[t], bes[t],
                                                 Ahi, Alo, ss1, ss2);
                k_gemm_mfma<0><<<g1, 256, 0, stream>>>(Ahi, Alo,
                    wt + 2097152, wt + 3145728, wt + 2097152, wt + 3145728, wt + 2097152, wt + 3145728,
                    b2s[t], b2s[t], b2s[t], Hbuf, BIG, BIG);
                k_out<<<cm / 4, 256, 0, stream>>>(x, idxc, idxc, idxc, Hbuf, outp, ss1, ss2);
            }
        }
    }
    (void)in_sizes; (void)n_in; (void)out_size;
}

// Round 14
// 330.137 us; speedup vs baseline: 4.3311x; 1.5601x over previous
//
#include <hip/hip_runtime.h>
#include <math.h>

#define C2 1024

typedef float f32x4 __attribute__((ext_vector_type(4)));
typedef _Float16 f16x8 __attribute__((ext_vector_type(8)));
typedef unsigned short u16x8 __attribute__((ext_vector_type(8)));

// ---- fp16 helper (RNE via cast) ----
__device__ __forceinline__ unsigned short f2h(float f) {
    _Float16 h = (_Float16)f;
    return __builtin_bit_cast(unsigned short, h);
}

__device__ __forceinline__ void gload16(const void* g, void* l) {
    __builtin_amdgcn_global_load_lds((const __attribute__((address_space(1))) void*)g,
                                     (__attribute__((address_space(3))) void*)l,
                                     16, 0, 0);
}

// type resolve helpers: t from (pos, s1, s2); start of that type's range
__device__ __forceinline__ int type_of(int pos, int s1, int s2) {
    return (pos >= s2) ? 2 : (pos >= s1) ? 1 : 0;
}
__device__ __forceinline__ int dim_of(int t) { return (t == 0) ? 8 : (t == 1) ? 14 : 18; }

// ---------------- conv: up to 6 fp32 1M-elem matrices -> fp16 ----------------
// grid = nmat*1024; w layout: per mat 1M halfs
__global__ __launch_bounds__(256) void k_conv(const float* __restrict__ s0, const float* __restrict__ s1,
                                              const float* __restrict__ s2, const float* __restrict__ s3,
                                              const float* __restrict__ s4, const float* __restrict__ s5,
                                              unsigned short* __restrict__ w) {
    int mat = blockIdx.x >> 10, bb = blockIdx.x & 1023;
    const float* src = (mat == 0) ? s0 : (mat == 1) ? s1 : (mat == 2) ? s2
                       : (mat == 3) ? s3 : (mat == 4) ? s4 : s5;
    int i = (bb * 256 + threadIdx.x) * 4;
    unsigned short* dst = w + (size_t)mat * 1048576;
    float4 v = *(const float4*)(src + i);
    ushort4 h;
    h.x = f2h(v.x); h.y = f2h(v.y); h.z = f2h(v.z); h.w = f2h(v.w);
    *(ushort4*)(dst + i) = h;
}

// ---------------- l2 = y^T S y -> A fp16. wave-per-atom, 4 atoms/block ----------------
__global__ __launch_bounds__(256) void k_l2(const float* __restrict__ x,
                                            const int* __restrict__ i0, const int* __restrict__ i1,
                                            const int* __restrict__ i2,
                                            const float* __restrict__ S0, const float* __restrict__ S1,
                                            const float* __restrict__ S2,
                                            unsigned short* __restrict__ Ah,
                                            int s1, int s2) {
    __shared__ float sS[324];
    __shared__ float sy[4][18][32];
    __shared__ float sSy[4][18][32];
    const int tid = threadIdx.x, g = tid >> 6, lane = tid & 63;
    const int a0 = blockIdx.x * 4;
    const int t = type_of(a0, s1, s2);
    const int d = dim_of(t);
    const int* idx = (t == 0) ? i0 : (t == 1) ? i1 : i2;
    const float* S = (t == 0) ? S0 : (t == 1) ? S1 : S2;
    const int start = (t == 0) ? 0 : (t == 1) ? s1 : s2;
    const int dd = d * d;
    for (int i = tid; i < dd; i += 256) sS[i] = S[i];
    const int a = a0 + g, la = a - start;
    const int nf4 = d * 8;
    for (int k = lane; k < nf4; k += 64) {
        int bi = k >> 3, f4 = (k & 7) * 4;
        int r = idx[la * d + bi];
        *(float4*)&sy[g][bi][f4] = *(const float4*)(x + (size_t)r * 32 + f4);
    }
    __syncthreads();
    for (int k = lane; k < d * 32; k += 64) {
        int i = k >> 5, m = k & 31;
        float acc = 0.f;
        for (int j = 0; j < d; ++j) acc += sS[i * d + j] * sy[g][j][m];
        sSy[g][i][m] = acc;
    }
    __syncthreads();
    const int c = lane >> 1, mb = (lane & 1) * 16;
    float acc[16];
#pragma unroll
    for (int mm = 0; mm < 16; ++mm) acc[mm] = 0.f;
    for (int i = 0; i < d; ++i) {
        float yc = sy[g][i][c];
#pragma unroll
        for (int mm = 0; mm < 16; ++mm) acc[mm] += yc * sSy[g][i][mb + mm];
    }
    u16x8 h0, h1;
#pragma unroll
    for (int mm = 0; mm < 8; ++mm) h0[mm] = f2h(acc[mm]);
#pragma unroll
    for (int mm = 0; mm < 8; ++mm) h1[mm] = f2h(acc[8 + mm]);
    size_t off = (size_t)a * C2 + lane * 16;
    *(u16x8*)(Ah + off) = h0;
    *(u16x8*)(Ah + off + 8) = h1;
}

// ---------------- MFMA GEMM fp16 single-pass: Out = [silu](A @ W^T + b) ----------------
// tile 128x128, BK=32, 4 waves of 64x64 (4x4 frags 16x16x32_f16)
// LDS linear (global_load_lds); k-slot XOR swizzle on BOTH global source and ds_read
template <int DO_SILU>
__global__ __launch_bounds__(256) void k_gemm_mfma(const unsigned short* __restrict__ A,
                                                   const unsigned short* __restrict__ W0,
                                                   const unsigned short* __restrict__ W1,
                                                   const unsigned short* __restrict__ W2,
                                                   const float* __restrict__ bias0, const float* __restrict__ bias1,
                                                   const float* __restrict__ bias2,
                                                   float* __restrict__ Out, int tb1, int tb2) {
    __shared__ short lds[8192];  // 16 KB: As | Ws
    short* As = lds;
    short* Ws = lds + 4096;

    const int tid = threadIdx.x;
    const int wid = tid >> 6, lane = tid & 63;
    const int bm = blockIdx.x, bn = blockIdx.y;
    const int wr = wid >> 1, wc = wid & 1;

    const unsigned short* W; const float* bias;
    if (bm >= tb2)      { W = W2; bias = bias2; }
    else if (bm >= tb1) { W = W1; bias = bias1; }
    else                { W = W0; bias = bias0; }

    size_t gA[2], gW[2];
    int ldsoff[2];
#pragma unroll
    for (int it = 0; it < 2; ++it) {
        int L = wid * 128 + it * 64 + lane;   // 16B-chunk index, 0..511
        int row = L >> 2, slot = L & 3;
        int sw = slot ^ ((row >> 1) & 3);
        gA[it] = (size_t)(bm * 128 + row) * C2 + sw * 8;
        gW[it] = (size_t)(bn * 128 + row) * C2 + sw * 8;
        ldsoff[it] = wid * 1024 + it * 512;   // shorts (wave-uniform base; HW adds lane*16B)
    }

    const int col = lane & 15, g = lane >> 4;
    int aoffs[4], woffs[4];
#pragma unroll
    for (int i = 0; i < 4; ++i) {
        int ra = wr * 64 + i * 16 + col;
        aoffs[i] = ra * 32 + (g ^ ((ra >> 1) & 3)) * 8;
        int rw = wc * 64 + i * 16 + col;
        woffs[i] = rw * 32 + (g ^ ((rw >> 1) & 3)) * 8;
    }

    f32x4 acc[4][4] = {};

    for (int k0 = 0; k0 < C2; k0 += 32) {
#pragma unroll
        for (int it = 0; it < 2; ++it) {
            gload16(A + gA[it] + k0, As + ldsoff[it]);
            gload16(W + gW[it] + k0, Ws + ldsoff[it]);
        }
        __syncthreads();
        f16x8 ah[4], wh[4];
#pragma unroll
        for (int i = 0; i < 4; ++i) {
            ah[i] = *(const f16x8*)(As + aoffs[i]);
            wh[i] = *(const f16x8*)(Ws + woffs[i]);
        }
#pragma unroll
        for (int mi = 0; mi < 4; ++mi)
#pragma unroll
            for (int ni = 0; ni < 4; ++ni)
                acc[mi][ni] = __builtin_amdgcn_mfma_f32_16x16x32_f16(ah[mi], wh[ni], acc[mi][ni], 0, 0, 0);
        __syncthreads();
    }

    float bv[4];
#pragma unroll
    for (int ni = 0; ni < 4; ++ni) bv[ni] = bias[bn * 128 + wc * 64 + ni * 16 + col];
#pragma unroll
    for (int mi = 0; mi < 4; ++mi)
#pragma unroll
        for (int ni = 0; ni < 4; ++ni) {
            int n = bn * 128 + wc * 64 + ni * 16 + col;
#pragma unroll
            for (int r = 0; r < 4; ++r) {
                int m = bm * 128 + wr * 64 + mi * 16 + g * 4 + r;
                float v = acc[mi][ni][r] + bv[ni];
                if (DO_SILU) v = v / (1.f + __expf(-v));
                Out[(size_t)m * C2 + n] = v;
            }
        }
}

// ---------------- LayerNorm: wave-per-row, 4 rows/block -> B fp16 ----------------
__global__ __launch_bounds__(256) void k_ln(const float* __restrict__ H,
                                            const float* __restrict__ g0, const float* __restrict__ g1,
                                            const float* __restrict__ g2,
                                            const float* __restrict__ b0, const float* __restrict__ b1,
                                            const float* __restrict__ b2,
                                            unsigned short* __restrict__ Bh,
                                            int s1, int s2) {
    const int tid = threadIdx.x, w = tid >> 6, lane = tid & 63;
    const int row = blockIdx.x * 4 + w;
    const int t = type_of(row, s1, s2);
    const float* gg = (t == 0) ? g0 : (t == 1) ? g1 : g2;
    const float* bb = (t == 0) ? b0 : (t == 1) ? b1 : b2;
    const float* rp = H + (size_t)row * C2;
    float4 v[4];
    float s = 0.f, s2v = 0.f;
#pragma unroll
    for (int k = 0; k < 4; ++k) {
        v[k] = *(const float4*)(rp + k * 256 + lane * 4);
        s += v[k].x + v[k].y + v[k].z + v[k].w;
        s2v += v[k].x * v[k].x + v[k].y * v[k].y + v[k].z * v[k].z + v[k].w * v[k].w;
    }
#pragma unroll
    for (int off = 1; off < 64; off <<= 1) {
        s += __shfl_xor(s, off);
        s2v += __shfl_xor(s2v, off);
    }
    float mean = s * (1.f / 1024.f);
    float var = s2v * (1.f / 1024.f) - mean * mean;
    float rstd = rsqrtf(var + 1e-5f);
#pragma unroll
    for (int k = 0; k < 4; ++k) {
        float4 gv = *(const float4*)(gg + k * 256 + lane * 4);
        float4 bv = *(const float4*)(bb + k * 256 + lane * 4);
        ushort4 h;
        h.x = f2h((v[k].x - mean) * rstd * gv.x + bv.x);
        h.y = f2h((v[k].y - mean) * rstd * gv.y + bv.y);
        h.z = f2h((v[k].z - mean) * rstd * gv.z + bv.z);
        h.w = f2h((v[k].w - mean) * rstd * gv.w + bv.w);
        size_t off2 = (size_t)row * C2 + k * 256 + lane * 4;
        *(ushort4*)(Bh + off2) = h;
    }
}

// ---------------- out = y @ l2' scatter. wave-per-atom, 4 atoms/block ----------------
__global__ __launch_bounds__(256) void k_out(const float* __restrict__ x,
                                             const int* __restrict__ i0, const int* __restrict__ i1,
                                             const int* __restrict__ i2,
                                             const float* __restrict__ L,
                                             float* __restrict__ out, int s1, int s2) {
    __shared__ float sL[4][C2];
    __shared__ float sy[4][18][32];
    const int tid = threadIdx.x, g = tid >> 6, lane = tid & 63;
    const int a0 = blockIdx.x * 4;
    const int t = type_of(a0, s1, s2);
    const int d = dim_of(t);
    const int* idx = (t == 0) ? i0 : (t == 1) ? i1 : i2;
    const int start = (t == 0) ? 0 : (t == 1) ? s1 : s2;
    const int a = a0 + g, la = a - start;
    for (int k = lane; k < 256; k += 64)
        *(float4*)&sL[g][k * 4] = *(const float4*)(L + (size_t)a * C2 + k * 4);
    const int nf4 = d * 8;
    for (int k = lane; k < nf4; k += 64) {
        int bi = k >> 3, f4 = (k & 7) * 4;
        int r = idx[la * d + bi];
        *(float4*)&sy[g][bi][f4] = *(const float4*)(x + (size_t)r * 32 + f4);
    }
    __syncthreads();
    for (int k = lane; k < nf4; k += 64) {
        int bi = k >> 3, m4 = (k & 7) * 4;
        float ax = 0.f, ay = 0.f, az = 0.f, aw = 0.f;
#pragma unroll
        for (int c = 0; c < 32; ++c) {
            float yv = sy[g][bi][c];
            float4 lv = *(const float4*)&sL[g][c * 32 + m4];
            ax += yv * lv.x; ay += yv * lv.y; az += yv * lv.z; aw += yv * lv.w;
        }
        int r = idx[la * d + bi];
        float4 o = {ax, ay, az, aw};
        *(float4*)(out + (size_t)r * 32 + m4) = o;
    }
}

extern "C" void kernel_launch(void* const* d_in, const int* in_sizes, int n_in,
                              void* d_out, int out_size, void* d_ws, size_t ws_size,
                              hipStream_t stream) {
    const float* x = (const float*)d_in[0];
    static const int DIMS[3] = {8, 14, 18};
    static const int NATOMS[3] = {8192, 8192, 4096};
    const size_t MiB = 1ull << 20;
    const int BIG = 0x40000000;
    char* p = (char*)d_ws;

    const int* idxs[3]; const float* Ss[3]; const float* W1s[3]; const float* b1s[3];
    const float* gs[3]; const float* bes[3]; const float* W2s[3]; const float* b2s[3];
    for (int t = 0; t < 3; ++t) {
        idxs[t] = (const int*)d_in[1 + 8 * t];
        Ss[t] = (const float*)d_in[2 + 8 * t];
        W1s[t] = (const float*)d_in[3 + 8 * t];
        b1s[t] = (const float*)d_in[4 + 8 * t];
        gs[t] = (const float*)d_in[5 + 8 * t];
        bes[t] = (const float*)d_in[6 + 8 * t];
        W2s[t] = (const float*)d_in[7 + 8 * t];
        b2s[t] = (const float*)d_in[8 + 8 * t];
    }
    float* outp = (float*)d_out;

    if (ws_size >= 132 * MiB) {
        // ---------- grouped path (proven round-12 flow, fp16 single-pass) ----------
        unsigned short* w = (unsigned short*)p;                // 12 MiB: 6 mats fp16
        unsigned short* Ah = (unsigned short*)(p + 12 * MiB);  // 40 MiB
        float* H = (float*)(p + 52 * MiB);                     // 80 MiB (end 132)
        // mats: {t0W1, t0W2, t1W1, t1W2, t2W1, t2W2}
        k_conv<<<6 * 1024, 256, 0, stream>>>(W1s[0], W2s[0], W1s[1], W2s[1], W1s[2], W2s[2], w);
        k_l2<<<5120, 256, 0, stream>>>(x, idxs[0], idxs[1], idxs[2], Ss[0], Ss[1], Ss[2],
                                       Ah, 8192, 16384);
        dim3 gg(160, 8);
        k_gemm_mfma<1><<<gg, 256, 0, stream>>>(Ah,
            w + 0 * 1048576, w + 2 * 1048576, w + 4 * 1048576,
            b1s[0], b1s[1], b1s[2], H, 64, 128);
        k_ln<<<5120, 256, 0, stream>>>(H, gs[0], gs[1], gs[2], bes[0], bes[1], bes[2],
                                       Ah, 8192, 16384);
        k_gemm_mfma<0><<<gg, 256, 0, stream>>>(Ah,
            w + 1 * 1048576, w + 3 * 1048576, w + 5 * 1048576,
            b2s[0], b2s[1], b2s[2], H, 64, 128);
        k_out<<<5120, 256, 0, stream>>>(x, idxs[0], idxs[1], idxs[2], H, outp, 8192, 16384);
    } else {
        // ---------- per-type fallback ----------
        unsigned short* wt = (unsigned short*)p;  // 4 MiB: W1 fp16 + W2 fp16
        char* dyn = p + 4 * MiB;
        for (int t = 0; t < 3; ++t) {
            int n = NATOMS[t], d = DIMS[t];
            size_t fullneed = 4 * MiB + (size_t)n * 6144;  // A 2KB + H 4KB per atom
            int nch = (ws_size >= fullneed) ? 1 : 2;
            int cm = n / nch;
            unsigned short* Ah = (unsigned short*)dyn;
            float* Hbuf = (float*)(dyn + (size_t)cm * 2048);
            int ss1 = (t == 0) ? BIG : 0;
            int ss2 = (t == 2) ? 0 : BIG;
            k_conv<<<2 * 1024, 256, 0, stream>>>(W1s[t], W2s[t], W1s[t], W1s[t], W1s[t], W1s[t], wt);
            for (int ch = 0; ch < nch; ++ch) {
                const int* idxc = idxs[t] + (size_t)(ch * cm) * d;
                k_l2<<<cm / 4, 256, 0, stream>>>(x, idxc, idxc, idxc, Ss[t], Ss[t], Ss[t],
                                                 Ah, ss1, ss2);
                dim3 g1(cm / 128, 8);
                k_gemm_mfma<1><<<g1, 256, 0, stream>>>(Ah,
                    wt + 0, wt + 0, wt + 0,
                    b1s[t], b1s[t], b1s[t], Hbuf, BIG, BIG);
                k_ln<<<cm / 4, 256, 0, stream>>>(Hbuf, gs[t], gs[t], gs[t], bes[t], bes[t], bes[t],
                                                 Ah, ss1, ss2);
                k_gemm_mfma<0><<<g1, 256, 0, stream>>>(Ah,
                    wt + 1048576, wt + 1048576, wt + 1048576,
                    b2s[t], b2s[t], b2s[t], Hbuf, BIG, BIG);
                k_out<<<cm / 4, 256, 0, stream>>>(x, idxc, idxc, idxc, Hbuf, outp, ss1, ss2);
            }
        }
    }
    (void)in_sizes; (void)n_in; (void)out_size;
}

// Round 15
// 329.903 us; speedup vs baseline: 4.3342x; 1.0007x over previous
//
#include <hip/hip_runtime.h>
#include <math.h>

#define C2 1024

typedef float f32x4 __attribute__((ext_vector_type(4)));
typedef _Float16 f16x8 __attribute__((ext_vector_type(8)));
typedef unsigned short u16x8 __attribute__((ext_vector_type(8)));

__device__ __forceinline__ unsigned short f2h(float f) {
    _Float16 h = (_Float16)f;
    return __builtin_bit_cast(unsigned short, h);
}
__device__ __forceinline__ float h2f(unsigned short u) {
    return (float)__builtin_bit_cast(_Float16, u);
}

__device__ __forceinline__ void gload16(const void* g, void* l) {
    __builtin_amdgcn_global_load_lds((const __attribute__((address_space(1))) void*)g,
                                     (__attribute__((address_space(3))) void*)l,
                                     16, 0, 0);
}

__device__ __forceinline__ int type_of(int pos, int s1, int s2) {
    return (pos >= s2) ? 2 : (pos >= s1) ? 1 : 0;
}
__device__ __forceinline__ int dim_of(int t) { return (t == 0) ? 8 : (t == 1) ? 14 : 18; }

// ---------------- conv: up to 6 fp32 1M-elem matrices -> fp16 ----------------
__global__ __launch_bounds__(256) void k_conv(const float* __restrict__ s0, const float* __restrict__ s1,
                                              const float* __restrict__ s2, const float* __restrict__ s3,
                                              const float* __restrict__ s4, const float* __restrict__ s5,
                                              unsigned short* __restrict__ w) {
    int mat = blockIdx.x >> 10, bb = blockIdx.x & 1023;
    const float* src = (mat == 0) ? s0 : (mat == 1) ? s1 : (mat == 2) ? s2
                       : (mat == 3) ? s3 : (mat == 4) ? s4 : s5;
    int i = (bb * 256 + threadIdx.x) * 4;
    unsigned short* dst = w + (size_t)mat * 1048576;
    float4 v = *(const float4*)(src + i);
    ushort4 h;
    h.x = f2h(v.x); h.y = f2h(v.y); h.z = f2h(v.z); h.w = f2h(v.w);
    *(ushort4*)(dst + i) = h;
}

// ---------------- l2 = y^T S y -> A fp16. wave-per-atom, 4 atoms/block ----------------
__global__ __launch_bounds__(256) void k_l2(const float* __restrict__ x,
                                            const int* __restrict__ i0, const int* __restrict__ i1,
                                            const int* __restrict__ i2,
                                            const float* __restrict__ S0, const float* __restrict__ S1,
                                            const float* __restrict__ S2,
                                            unsigned short* __restrict__ Ah,
                                            int s1, int s2) {
    __shared__ float sS[324];
    __shared__ float sy[4][18][32];
    __shared__ float sSy[4][18][32];
    const int tid = threadIdx.x, g = tid >> 6, lane = tid & 63;
    const int a0 = blockIdx.x * 4;
    const int t = type_of(a0, s1, s2);
    const int d = dim_of(t);
    const int* idx = (t == 0) ? i0 : (t == 1) ? i1 : i2;
    const float* S = (t == 0) ? S0 : (t == 1) ? S1 : S2;
    const int start = (t == 0) ? 0 : (t == 1) ? s1 : s2;
    const int dd = d * d;
    for (int i = tid; i < dd; i += 256) sS[i] = S[i];
    const int a = a0 + g, la = a - start;
    const int nf4 = d * 8;
    for (int k = lane; k < nf4; k += 64) {
        int bi = k >> 3, f4 = (k & 7) * 4;
        int r = idx[la * d + bi];
        *(float4*)&sy[g][bi][f4] = *(const float4*)(x + (size_t)r * 32 + f4);
    }
    __syncthreads();
    for (int k = lane; k < d * 32; k += 64) {
        int i = k >> 5, m = k & 31;
        float acc = 0.f;
        for (int j = 0; j < d; ++j) acc += sS[i * d + j] * sy[g][j][m];
        sSy[g][i][m] = acc;
    }
    __syncthreads();
    const int c = lane >> 1, mb = (lane & 1) * 16;
    float acc[16];
#pragma unroll
    for (int mm = 0; mm < 16; ++mm) acc[mm] = 0.f;
    for (int i = 0; i < d; ++i) {
        float yc = sy[g][i][c];
#pragma unroll
        for (int mm = 0; mm < 16; ++mm) acc[mm] += yc * sSy[g][i][mb + mm];
    }
    u16x8 h0, h1;
#pragma unroll
    for (int mm = 0; mm < 8; ++mm) h0[mm] = f2h(acc[mm]);
#pragma unroll
    for (int mm = 0; mm < 8; ++mm) h1[mm] = f2h(acc[8 + mm]);
    size_t off = (size_t)a * C2 + lane * 16;
    *(u16x8*)(Ah + off) = h0;
    *(u16x8*)(Ah + off + 8) = h1;
}

// ---------------- MFMA GEMM fp16: Out(fp16) = [silu](A @ W^T + b) ----------------
// tile 128x128, BK=32, 4 waves of 64x64. LDS-staged coalesced fp16 epilogue.
template <int DO_SILU>
__global__ __launch_bounds__(256) void k_gemm_mfma(const unsigned short* __restrict__ A,
                                                   const unsigned short* __restrict__ W0,
                                                   const unsigned short* __restrict__ W1,
                                                   const unsigned short* __restrict__ W2,
                                                   const float* __restrict__ bias0, const float* __restrict__ bias1,
                                                   const float* __restrict__ bias2,
                                                   unsigned short* __restrict__ Out, int tb1, int tb2) {
    __shared__ short lds[8704];  // K-loop: 8192 shorts (As|Ws). Epilogue: [64][136]
    short* As = lds;
    short* Ws = lds + 4096;

    const int tid = threadIdx.x;
    const int wid = tid >> 6, lane = tid & 63;
    const int bm = blockIdx.x, bn = blockIdx.y;
    const int wr = wid >> 1, wc = wid & 1;

    const unsigned short* W; const float* bias;
    if (bm >= tb2)      { W = W2; bias = bias2; }
    else if (bm >= tb1) { W = W1; bias = bias1; }
    else                { W = W0; bias = bias0; }

    size_t gA[2], gW[2];
    int ldsoff[2];
#pragma unroll
    for (int it = 0; it < 2; ++it) {
        int L = wid * 128 + it * 64 + lane;   // 16B-chunk index, 0..511
        int row = L >> 2, slot = L & 3;
        int sw = slot ^ ((row >> 1) & 3);
        gA[it] = (size_t)(bm * 128 + row) * C2 + sw * 8;
        gW[it] = (size_t)(bn * 128 + row) * C2 + sw * 8;
        ldsoff[it] = wid * 1024 + it * 512;
    }

    const int col = lane & 15, g = lane >> 4;
    int aoffs[4], woffs[4];
#pragma unroll
    for (int i = 0; i < 4; ++i) {
        int ra = wr * 64 + i * 16 + col;
        aoffs[i] = ra * 32 + (g ^ ((ra >> 1) & 3)) * 8;
        int rw = wc * 64 + i * 16 + col;
        woffs[i] = rw * 32 + (g ^ ((rw >> 1) & 3)) * 8;
    }

    f32x4 acc[4][4] = {};

    for (int k0 = 0; k0 < C2; k0 += 32) {
#pragma unroll
        for (int it = 0; it < 2; ++it) {
            gload16(A + gA[it] + k0, As + ldsoff[it]);
            gload16(W + gW[it] + k0, Ws + ldsoff[it]);
        }
        __syncthreads();
        f16x8 ah[4], wh[4];
#pragma unroll
        for (int i = 0; i < 4; ++i) {
            ah[i] = *(const f16x8*)(As + aoffs[i]);
            wh[i] = *(const f16x8*)(Ws + woffs[i]);
        }
#pragma unroll
        for (int mi = 0; mi < 4; ++mi)
#pragma unroll
            for (int ni = 0; ni < 4; ++ni)
                acc[mi][ni] = __builtin_amdgcn_mfma_f32_16x16x32_f16(ah[mi], wh[ni], acc[mi][ni], 0, 0, 0);
        __syncthreads();
    }

    float bv[4];
#pragma unroll
    for (int ni = 0; ni < 4; ++ni) bv[ni] = bias[bn * 128 + wc * 64 + ni * 16 + col];

    // epilogue: 2 half-passes through LDS [64][136] shorts (row stride 272B:
    // 16B-aligned, g-row alias 2-way = free), then coalesced ushort8 stores
#pragma unroll
    for (int hp = 0; hp < 2; ++hp) {
        __syncthreads();
#pragma unroll
        for (int mh = 0; mh < 2; ++mh) {
            int mi = hp * 2 + mh;
#pragma unroll
            for (int ni = 0; ni < 4; ++ni)
#pragma unroll
                for (int r = 0; r < 4; ++r) {
                    float v = acc[mi][ni][r] + bv[ni];
                    if (DO_SILU) v = v / (1.f + __expf(-v));
                    int row = mh * 16 + g * 4 + r;           // 0..31
                    int colc = wc * 64 + ni * 16 + col;      // 0..127
                    lds[(wr * 32 + row) * 136 + colc] = (short)f2h(v);
                }
        }
        __syncthreads();
#pragma unroll
        for (int i = 0; i < 4; ++i) {
            int ci = tid + i * 256;            // 0..1023 chunks of 8 shorts
            int wrp = ci >> 9, rem = ci & 511;
            int row = rem >> 4, c8 = rem & 15;
            u16x8 val = *(u16x8*)&lds[(wrp * 32 + row) * 136 + c8 * 8];
            int grow = bm * 128 + wrp * 64 + hp * 32 + row;
            int gcol = bn * 128 + c8 * 8;
            *(u16x8*)&Out[(size_t)grow * C2 + gcol] = val;
        }
    }
}

// ---------------- LayerNorm: wave-per-row, fp16 in -> fp16 A out ----------------
__global__ __launch_bounds__(256) void k_ln(const unsigned short* __restrict__ H,
                                            const float* __restrict__ g0, const float* __restrict__ g1,
                                            const float* __restrict__ g2,
                                            const float* __restrict__ b0, const float* __restrict__ b1,
                                            const float* __restrict__ b2,
                                            unsigned short* __restrict__ Bh,
                                            int s1, int s2) {
    const int tid = threadIdx.x, w = tid >> 6, lane = tid & 63;
    const int row = blockIdx.x * 4 + w;
    const int t = type_of(row, s1, s2);
    const float* gg = (t == 0) ? g0 : (t == 1) ? g1 : g2;
    const float* bb = (t == 0) ? b0 : (t == 1) ? b1 : b2;
    const unsigned short* rp = H + (size_t)row * C2 + lane * 16;
    u16x8 hv0 = *(const u16x8*)rp;
    u16x8 hv1 = *(const u16x8*)(rp + 8);
    float v[16];
#pragma unroll
    for (int k = 0; k < 8; ++k) v[k] = h2f(hv0[k]);
#pragma unroll
    for (int k = 0; k < 8; ++k) v[8 + k] = h2f(hv1[k]);
    float s = 0.f, s2v = 0.f;
#pragma unroll
    for (int k = 0; k < 16; ++k) { s += v[k]; s2v += v[k] * v[k]; }
#pragma unroll
    for (int off = 1; off < 64; off <<= 1) {
        s += __shfl_xor(s, off);
        s2v += __shfl_xor(s2v, off);
    }
    float mean = s * (1.f / 1024.f);
    float var = s2v * (1.f / 1024.f) - mean * mean;
    float rstd = rsqrtf(var + 1e-5f);
    u16x8 o0, o1;
#pragma unroll
    for (int q = 0; q < 4; ++q) {
        float4 gv = *(const float4*)(gg + lane * 16 + q * 4);
        float4 bv = *(const float4*)(bb + lane * 16 + q * 4);
        float r0 = (v[q * 4 + 0] - mean) * rstd * gv.x + bv.x;
        float r1 = (v[q * 4 + 1] - mean) * rstd * gv.y + bv.y;
        float r2 = (v[q * 4 + 2] - mean) * rstd * gv.z + bv.z;
        float r3 = (v[q * 4 + 3] - mean) * rstd * gv.w + bv.w;
        if (q < 2) {
            o0[q * 4 + 0] = f2h(r0); o0[q * 4 + 1] = f2h(r1);
            o0[q * 4 + 2] = f2h(r2); o0[q * 4 + 3] = f2h(r3);
        } else {
            o1[(q - 2) * 4 + 0] = f2h(r0); o1[(q - 2) * 4 + 1] = f2h(r1);
            o1[(q - 2) * 4 + 2] = f2h(r2); o1[(q - 2) * 4 + 3] = f2h(r3);
        }
    }
    unsigned short* op = Bh + (size_t)row * C2 + lane * 16;
    *(u16x8*)op = o0;
    *(u16x8*)(op + 8) = o1;
}

// ---------------- out = y @ l2' scatter. L fp16. wave-per-atom, 4 atoms/block ----------------
__global__ __launch_bounds__(256) void k_out(const float* __restrict__ x,
                                             const int* __restrict__ i0, const int* __restrict__ i1,
                                             const int* __restrict__ i2,
                                             const unsigned short* __restrict__ L,
                                             float* __restrict__ out, int s1, int s2) {
    __shared__ float sL[4][C2];
    __shared__ float sy[4][18][32];
    const int tid = threadIdx.x, g = tid >> 6, lane = tid & 63;
    const int a0 = blockIdx.x * 4;
    const int t = type_of(a0, s1, s2);
    const int d = dim_of(t);
    const int* idx = (t == 0) ? i0 : (t == 1) ? i1 : i2;
    const int start = (t == 0) ? 0 : (t == 1) ? s1 : s2;
    const int a = a0 + g, la = a - start;
    for (int k = lane; k < 128; k += 64) {   // 128 chunks of 8 halfs
        u16x8 hv = *(const u16x8*)(L + (size_t)a * C2 + k * 8);
#pragma unroll
        for (int q = 0; q < 8; ++q) sL[g][k * 8 + q] = h2f(hv[q]);
    }
    const int nf4 = d * 8;
    for (int k = lane; k < nf4; k += 64) {
        int bi = k >> 3, f4 = (k & 7) * 4;
        int r = idx[la * d + bi];
        *(float4*)&sy[g][bi][f4] = *(const float4*)(x + (size_t)r * 32 + f4);
    }
    __syncthreads();
    for (int k = lane; k < nf4; k += 64) {
        int bi = k >> 3, m4 = (k & 7) * 4;
        float ax = 0.f, ay = 0.f, az = 0.f, aw = 0.f;
#pragma unroll
        for (int c = 0; c < 32; ++c) {
            float yv = sy[g][bi][c];
            float4 lv = *(const float4*)&sL[g][c * 32 + m4];
            ax += yv * lv.x; ay += yv * lv.y; az += yv * lv.z; aw += yv * lv.w;
        }
        int r = idx[la * d + bi];
        float4 o = {ax, ay, az, aw};
        *(float4*)(out + (size_t)r * 32 + m4) = o;
    }
}

extern "C" void kernel_launch(void* const* d_in, const int* in_sizes, int n_in,
                              void* d_out, int out_size, void* d_ws, size_t ws_size,
                              hipStream_t stream) {
    const float* x = (const float*)d_in[0];
    static const int DIMS[3] = {8, 14, 18};
    static const int NATOMS[3] = {8192, 8192, 4096};
    const size_t MiB = 1ull << 20;
    const int BIG = 0x40000000;
    char* p = (char*)d_ws;

    const int* idxs[3]; const float* Ss[3]; const float* W1s[3]; const float* b1s[3];
    const float* gs[3]; const float* bes[3]; const float* W2s[3]; const float* b2s[3];
    for (int t = 0; t < 3; ++t) {
        idxs[t] = (const int*)d_in[1 + 8 * t];
        Ss[t] = (const float*)d_in[2 + 8 * t];
        W1s[t] = (const float*)d_in[3 + 8 * t];
        b1s[t] = (const float*)d_in[4 + 8 * t];
        gs[t] = (const float*)d_in[5 + 8 * t];
        bes[t] = (const float*)d_in[6 + 8 * t];
        W2s[t] = (const float*)d_in[7 + 8 * t];
        b2s[t] = (const float*)d_in[8 + 8 * t];
    }
    float* outp = (float*)d_out;

    if (ws_size >= 92 * MiB) {
        // ---------- grouped path: fp16 H throughout ----------
        unsigned short* w = (unsigned short*)p;                 // 12 MiB: 6 mats fp16
        unsigned short* Ah = (unsigned short*)(p + 12 * MiB);   // 40 MiB
        unsigned short* H = (unsigned short*)(p + 52 * MiB);    // 40 MiB (end 92)
        k_conv<<<6 * 1024, 256, 0, stream>>>(W1s[0], W2s[0], W1s[1], W2s[1], W1s[2], W2s[2], w);
        k_l2<<<5120, 256, 0, stream>>>(x, idxs[0], idxs[1], idxs[2], Ss[0], Ss[1], Ss[2],
                                       Ah, 8192, 16384);
        dim3 gg(160, 8);
        k_gemm_mfma<1><<<gg, 256, 0, stream>>>(Ah,
            w + 0 * 1048576, w + 2 * 1048576, w + 4 * 1048576,
            b1s[0], b1s[1], b1s[2], H, 64, 128);
        k_ln<<<5120, 256, 0, stream>>>(H, gs[0], gs[1], gs[2], bes[0], bes[1], bes[2],
                                       Ah, 8192, 16384);
        k_gemm_mfma<0><<<gg, 256, 0, stream>>>(Ah,
            w + 1 * 1048576, w + 3 * 1048576, w + 5 * 1048576,
            b2s[0], b2s[1], b2s[2], H, 64, 128);
        k_out<<<5120, 256, 0, stream>>>(x, idxs[0], idxs[1], idxs[2], H, outp, 8192, 16384);
    } else {
        // ---------- per-type fallback ----------
        unsigned short* wt = (unsigned short*)p;  // 4 MiB: W1 fp16 + W2 fp16
        char* dyn = p + 4 * MiB;
        for (int t = 0; t < 3; ++t) {
            int n = NATOMS[t], d = DIMS[t];
            size_t fullneed = 4 * MiB + (size_t)n * 4096;  // A 2KB + H 2KB per atom
            int nch = (ws_size >= fullneed) ? 1 : 2;
            int cm = n / nch;
            unsigned short* Ah = (unsigned short*)dyn;
            unsigned short* Hbuf = (unsigned short*)(dyn + (size_t)cm * 2048);
            int ss1 = (t == 0) ? BIG : 0;
            int ss2 = (t == 2) ? 0 : BIG;
            k_conv<<<2 * 1024, 256, 0, stream>>>(W1s[t], W2s[t], W1s[t], W1s[t], W1s[t], W1s[t], wt);
            for (int ch = 0; ch < nch; ++ch) {
                const int* idxc = idxs[t] + (size_t)(ch * cm) * d;
                k_l2<<<cm / 4, 256, 0, stream>>>(x, idxc, idxc, idxc, Ss[t], Ss[t], Ss[t],
                                                 Ah, ss1, ss2);
                dim3 g1(cm / 128, 8);
                k_gemm_mfma<1><<<g1, 256, 0, stream>>>(Ah,
                    wt + 0, wt + 0, wt + 0,
                    b1s[t], b1s[t], b1s[t], Hbuf, BIG, BIG);
                k_ln<<<cm / 4, 256, 0, stream>>>(Hbuf, gs[t], gs[t], gs[t], bes[t], bes[t], bes[t],
                                                 Ah, ss1, ss2);
                k_gemm_mfma<0><<<g1, 256, 0, stream>>>(Ah,
                    wt + 1048576, wt + 1048576, wt + 1048576,
                    b2s[t], b2s[t], b2s[t], Hbuf, BIG, BIG);
                k_out<<<cm / 4, 256, 0, stream>>>(x, idxc, idxc, idxc, Hbuf, outp, ss1, ss2);
            }
        }
    }
    (void)in_sizes; (void)n_in; (void)out_size;
}

// Round 16
// 322.920 us; speedup vs baseline: 4.4279x; 1.0216x over previous
//
#include <hip/hip_runtime.h>
#include <math.h>

#define C2 1024

typedef float f32x4 __attribute__((ext_vector_type(4)));
typedef _Float16 f16x8 __attribute__((ext_vector_type(8)));
typedef unsigned short u16x8 __attribute__((ext_vector_type(8)));

__device__ __forceinline__ unsigned short f2h(float f) {
    _Float16 h = (_Float16)f;
    return __builtin_bit_cast(unsigned short, h);
}
__device__ __forceinline__ float h2f(unsigned short u) {
    return (float)__builtin_bit_cast(_Float16, u);
}

__device__ __forceinline__ void gload16(const void* g, void* l) {
    __builtin_amdgcn_global_load_lds((const __attribute__((address_space(1))) void*)g,
                                     (__attribute__((address_space(3))) void*)l,
                                     16, 0, 0);
}

__device__ __forceinline__ int type_of(int pos, int s1, int s2) {
    return (pos >= s2) ? 2 : (pos >= s1) ? 1 : 0;
}
__device__ __forceinline__ int dim_of(int t) { return (t == 0) ? 8 : (t == 1) ? 14 : 18; }

// ---------------- front: conv (blocks < nconv) + l2 (blocks >= nconv) ----------------
// conv: mat = bid>>10, 1024 blocks/mat, fp32 -> fp16, per mat 1M halfs
// l2:   wave-per-atom, 4 atoms/block -> A fp16
__global__ __launch_bounds__(256) void k_front(const float* __restrict__ x,
                                               const int* __restrict__ i0, const int* __restrict__ i1,
                                               const int* __restrict__ i2,
                                               const float* __restrict__ S0, const float* __restrict__ S1,
                                               const float* __restrict__ S2,
                                               unsigned short* __restrict__ Ah,
                                               int s1, int s2,
                                               const float* __restrict__ w0, const float* __restrict__ w1,
                                               const float* __restrict__ w2, const float* __restrict__ w3,
                                               const float* __restrict__ w4, const float* __restrict__ w5,
                                               unsigned short* __restrict__ w,
                                               int nconv) {
    __shared__ float sS[324];
    __shared__ float sy[4][18][32];
    __shared__ float sSy[4][18][32];
    const int tid = threadIdx.x;
    if ((int)blockIdx.x < nconv) {
        int mat = blockIdx.x >> 10, bb = blockIdx.x & 1023;
        const float* src = (mat == 0) ? w0 : (mat == 1) ? w1 : (mat == 2) ? w2
                           : (mat == 3) ? w3 : (mat == 4) ? w4 : w5;
        int i = (bb * 256 + tid) * 4;
        unsigned short* dst = w + (size_t)mat * 1048576;
        float4 v = *(const float4*)(src + i);
        ushort4 h;
        h.x = f2h(v.x); h.y = f2h(v.y); h.z = f2h(v.z); h.w = f2h(v.w);
        *(ushort4*)(dst + i) = h;
        return;
    }
    const int bid = blockIdx.x - nconv;
    const int g = tid >> 6, lane = tid & 63;
    const int a0 = bid * 4;
    const int t = type_of(a0, s1, s2);
    const int d = dim_of(t);
    const int* idx = (t == 0) ? i0 : (t == 1) ? i1 : i2;
    const float* S = (t == 0) ? S0 : (t == 1) ? S1 : S2;
    const int start = (t == 0) ? 0 : (t == 1) ? s1 : s2;
    const int dd = d * d;
    for (int i = tid; i < dd; i += 256) sS[i] = S[i];
    const int a = a0 + g, la = a - start;
    const int nf4 = d * 8;
    for (int k = lane; k < nf4; k += 64) {
        int bi = k >> 3, f4 = (k & 7) * 4;
        int r = idx[la * d + bi];
        *(float4*)&sy[g][bi][f4] = *(const float4*)(x + (size_t)r * 32 + f4);
    }
    __syncthreads();
    for (int k = lane; k < d * 32; k += 64) {
        int i = k >> 5, m = k & 31;
        float acc = 0.f;
        for (int j = 0; j < d; ++j) acc += sS[i * d + j] * sy[g][j][m];
        sSy[g][i][m] = acc;
    }
    __syncthreads();
    const int c = lane >> 1, mb = (lane & 1) * 16;
    float acc[16];
#pragma unroll
    for (int mm = 0; mm < 16; ++mm) acc[mm] = 0.f;
    for (int i = 0; i < d; ++i) {
        float yc = sy[g][i][c];
#pragma unroll
        for (int mm = 0; mm < 16; ++mm) acc[mm] += yc * sSy[g][i][mb + mm];
    }
    u16x8 h0, h1;
#pragma unroll
    for (int mm = 0; mm < 8; ++mm) h0[mm] = f2h(acc[mm]);
#pragma unroll
    for (int mm = 0; mm < 8; ++mm) h1[mm] = f2h(acc[8 + mm]);
    size_t off = (size_t)a * C2 + lane * 16;
    *(u16x8*)(Ah + off) = h0;
    *(u16x8*)(Ah + off + 8) = h1;
}

// ---------------- MFMA GEMM fp16, 2-phase double-buffered LDS ----------------
// tile 128x128, BK=32, 4 waves of 64x64. Issue next-tile stage BEFORE compute;
// one barrier per K-step (drain overlaps 16 MFMA + 8 ds_read). LDS 32 KB.
template <int DO_SILU>
__global__ __launch_bounds__(256) void k_gemm_mfma(const unsigned short* __restrict__ A,
                                                   const unsigned short* __restrict__ W0,
                                                   const unsigned short* __restrict__ W1,
                                                   const unsigned short* __restrict__ W2,
                                                   const float* __restrict__ bias0, const float* __restrict__ bias1,
                                                   const float* __restrict__ bias2,
                                                   unsigned short* __restrict__ Out, int tb1, int tb2) {
    __shared__ short lds[16384];  // 2 x (As 4096 | Ws 4096); epilogue reuses [0..8703]

    const int tid = threadIdx.x;
    const int wid = tid >> 6, lane = tid & 63;
    const int bm = blockIdx.x, bn = blockIdx.y;
    const int wr = wid >> 1, wc = wid & 1;

    const unsigned short* W; const float* bias;
    if (bm >= tb2)      { W = W2; bias = bias2; }
    else if (bm >= tb1) { W = W1; bias = bias1; }
    else                { W = W0; bias = bias0; }

    size_t gA[2], gW[2];
    int ldsoff[2];
#pragma unroll
    for (int it = 0; it < 2; ++it) {
        int L = wid * 128 + it * 64 + lane;   // 16B-chunk index, 0..511
        int row = L >> 2, slot = L & 3;
        int sw = slot ^ ((row >> 1) & 3);
        gA[it] = (size_t)(bm * 128 + row) * C2 + sw * 8;
        gW[it] = (size_t)(bn * 128 + row) * C2 + sw * 8;
        ldsoff[it] = wid * 1024 + it * 512;   // shorts within a 4096-short tile
    }

    const int col = lane & 15, g = lane >> 4;
    int aoffs[4], woffs[4];
#pragma unroll
    for (int i = 0; i < 4; ++i) {
        int ra = wr * 64 + i * 16 + col;
        aoffs[i] = ra * 32 + (g ^ ((ra >> 1) & 3)) * 8;
        int rw = wc * 64 + i * 16 + col;
        woffs[i] = rw * 32 + (g ^ ((rw >> 1) & 3)) * 8;
    }

    f32x4 acc[4][4] = {};

    // prologue: stage tile 0 into buffer 0, drain, barrier
#pragma unroll
    for (int it = 0; it < 2; ++it) {
        gload16(A + gA[it], lds + ldsoff[it]);
        gload16(W + gW[it], lds + 4096 + ldsoff[it]);
    }
    __syncthreads();

    int base = 0;
    for (int k0 = 0; k0 < C2; k0 += 32) {
        int nbase = base ^ 8192;
        if (k0 + 32 < C2) {
#pragma unroll
            for (int it = 0; it < 2; ++it) {
                gload16(A + gA[it] + k0 + 32, lds + nbase + ldsoff[it]);
                gload16(W + gW[it] + k0 + 32, lds + nbase + 4096 + ldsoff[it]);
            }
        }
        f16x8 ah[4], wh[4];
#pragma unroll
        for (int i = 0; i < 4; ++i) {
            ah[i] = *(const f16x8*)(lds + base + aoffs[i]);
            wh[i] = *(const f16x8*)(lds + base + 4096 + woffs[i]);
        }
#pragma unroll
        for (int mi = 0; mi < 4; ++mi)
#pragma unroll
            for (int ni = 0; ni < 4; ++ni)
                acc[mi][ni] = __builtin_amdgcn_mfma_f32_16x16x32_f16(ah[mi], wh[ni], acc[mi][ni], 0, 0, 0);
        __syncthreads();   // drains next-tile loads (overlapped with the MFMA above)
        base = nbase;
    }

    float bv[4];
#pragma unroll
    for (int ni = 0; ni < 4; ++ni) bv[ni] = bias[bn * 128 + wc * 64 + ni * 16 + col];

    // epilogue: 2 half-passes through LDS [64][136] shorts, coalesced ushort8 stores
#pragma unroll
    for (int hp = 0; hp < 2; ++hp) {
        __syncthreads();
#pragma unroll
        for (int mh = 0; mh < 2; ++mh) {
            int mi = hp * 2 + mh;
#pragma unroll
            for (int ni = 0; ni < 4; ++ni)
#pragma unroll
                for (int r = 0; r < 4; ++r) {
                    float v = acc[mi][ni][r] + bv[ni];
                    if (DO_SILU) v = v / (1.f + __expf(-v));
                    int row = mh * 16 + g * 4 + r;           // 0..31
                    int colc = wc * 64 + ni * 16 + col;      // 0..127
                    lds[(wr * 32 + row) * 136 + colc] = (short)f2h(v);
                }
        }
        __syncthreads();
#pragma unroll
        for (int i = 0; i < 4; ++i) {
            int ci = tid + i * 256;            // 0..1023 chunks of 8 shorts
            int wrp = ci >> 9, rem = ci & 511;
            int row = rem >> 4, c8 = rem & 15;
            u16x8 val = *(u16x8*)&lds[(wrp * 32 + row) * 136 + c8 * 8];
            int grow = bm * 128 + wrp * 64 + hp * 32 + row;
            int gcol = bn * 128 + c8 * 8;
            *(u16x8*)&Out[(size_t)grow * C2 + gcol] = val;
        }
    }
}

// ---------------- LayerNorm: wave-per-row, fp16 in -> fp16 A out ----------------
__global__ __launch_bounds__(256) void k_ln(const unsigned short* __restrict__ H,
                                            const float* __restrict__ g0, const float* __restrict__ g1,
                                            const float* __restrict__ g2,
                                            const float* __restrict__ b0, const float* __restrict__ b1,
                                            const float* __restrict__ b2,
                                            unsigned short* __restrict__ Bh,
                                            int s1, int s2) {
    const int tid = threadIdx.x, w = tid >> 6, lane = tid & 63;
    const int row = blockIdx.x * 4 + w;
    const int t = type_of(row, s1, s2);
    const float* gg = (t == 0) ? g0 : (t == 1) ? g1 : g2;
    const float* bb = (t == 0) ? b0 : (t == 1) ? b1 : b2;
    const unsigned short* rp = H + (size_t)row * C2 + lane * 16;
    u16x8 hv0 = *(const u16x8*)rp;
    u16x8 hv1 = *(const u16x8*)(rp + 8);
    float v[16];
#pragma unroll
    for (int k = 0; k < 8; ++k) v[k] = h2f(hv0[k]);
#pragma unroll
    for (int k = 0; k < 8; ++k) v[8 + k] = h2f(hv1[k]);
    float s = 0.f, s2v = 0.f;
#pragma unroll
    for (int k = 0; k < 16; ++k) { s += v[k]; s2v += v[k] * v[k]; }
#pragma unroll
    for (int off = 1; off < 64; off <<= 1) {
        s += __shfl_xor(s, off);
        s2v += __shfl_xor(s2v, off);
    }
    float mean = s * (1.f / 1024.f);
    float var = s2v * (1.f / 1024.f) - mean * mean;
    float rstd = rsqrtf(var + 1e-5f);
    u16x8 o0, o1;
#pragma unroll
    for (int q = 0; q < 4; ++q) {
        float4 gv = *(const float4*)(gg + lane * 16 + q * 4);
        float4 bv = *(const float4*)(bb + lane * 16 + q * 4);
        float r0 = (v[q * 4 + 0] - mean) * rstd * gv.x + bv.x;
        float r1 = (v[q * 4 + 1] - mean) * rstd * gv.y + bv.y;
        float r2 = (v[q * 4 + 2] - mean) * rstd * gv.z + bv.z;
        float r3 = (v[q * 4 + 3] - mean) * rstd * gv.w + bv.w;
        if (q < 2) {
            o0[q * 4 + 0] = f2h(r0); o0[q * 4 + 1] = f2h(r1);
            o0[q * 4 + 2] = f2h(r2); o0[q * 4 + 3] = f2h(r3);
        } else {
            o1[(q - 2) * 4 + 0] = f2h(r0); o1[(q - 2) * 4 + 1] = f2h(r1);
            o1[(q - 2) * 4 + 2] = f2h(r2); o1[(q - 2) * 4 + 3] = f2h(r3);
        }
    }
    unsigned short* op = Bh + (size_t)row * C2 + lane * 16;
    *(u16x8*)op = o0;
    *(u16x8*)(op + 8) = o1;
}

// ---------------- out = y @ l2' scatter. L fp16. wave-per-atom, 4 atoms/block ----------------
__global__ __launch_bounds__(256) void k_out(const float* __restrict__ x,
                                             const int* __restrict__ i0, const int* __restrict__ i1,
                                             const int* __restrict__ i2,
                                             const unsigned short* __restrict__ L,
                                             float* __restrict__ out, int s1, int s2) {
    __shared__ float sL[4][C2];
    __shared__ float sy[4][18][32];
    const int tid = threadIdx.x, g = tid >> 6, lane = tid & 63;
    const int a0 = blockIdx.x * 4;
    const int t = type_of(a0, s1, s2);
    const int d = dim_of(t);
    const int* idx = (t == 0) ? i0 : (t == 1) ? i1 : i2;
    const int start = (t == 0) ? 0 : (t == 1) ? s1 : s2;
    const int a = a0 + g, la = a - start;
    for (int k = lane; k < 128; k += 64) {   // 128 chunks of 8 halfs
        u16x8 hv = *(const u16x8*)(L + (size_t)a * C2 + k * 8);
#pragma unroll
        for (int q = 0; q < 8; ++q) sL[g][k * 8 + q] = h2f(hv[q]);
    }
    const int nf4 = d * 8;
    for (int k = lane; k < nf4; k += 64) {
        int bi = k >> 3, f4 = (k & 7) * 4;
        int r = idx[la * d + bi];
        *(float4*)&sy[g][bi][f4] = *(const float4*)(x + (size_t)r * 32 + f4);
    }
    __syncthreads();
    for (int k = lane; k < nf4; k += 64) {
        int bi = k >> 3, m4 = (k & 7) * 4;
        float ax = 0.f, ay = 0.f, az = 0.f, aw = 0.f;
#pragma unroll
        for (int c = 0; c < 32; ++c) {
            float yv = sy[g][bi][c];
            float4 lv = *(const float4*)&sL[g][c * 32 + m4];
            ax += yv * lv.x; ay += yv * lv.y; az += yv * lv.z; aw += yv * lv.w;
        }
        int r = idx[la * d + bi];
        float4 o = {ax, ay, az, aw};
        *(float4*)(out + (size_t)r * 32 + m4) = o;
    }
}

extern "C" void kernel_launch(void* const* d_in, const int* in_sizes, int n_in,
                              void* d_out, int out_size, void* d_ws, size_t ws_size,
                              hipStream_t stream) {
    const float* x = (const float*)d_in[0];
    static const int DIMS[3] = {8, 14, 18};
    static const int NATOMS[3] = {8192, 8192, 4096};
    const size_t MiB = 1ull << 20;
    const int BIG = 0x40000000;
    char* p = (char*)d_ws;

    const int* idxs[3]; const float* Ss[3]; const float* W1s[3]; const float* b1s[3];
    const float* gs[3]; const float* bes[3]; const float* W2s[3]; const float* b2s[3];
    for (int t = 0; t < 3; ++t) {
        idxs[t] = (const int*)d_in[1 + 8 * t];
        Ss[t] = (const float*)d_in[2 + 8 * t];
        W1s[t] = (const float*)d_in[3 + 8 * t];
        b1s[t] = (const float*)d_in[4 + 8 * t];
        gs[t] = (const float*)d_in[5 + 8 * t];
        bes[t] = (const float*)d_in[6 + 8 * t];
        W2s[t] = (const float*)d_in[7 + 8 * t];
        b2s[t] = (const float*)d_in[8 + 8 * t];
    }
    float* outp = (float*)d_out;

    if (ws_size >= 92 * MiB) {
        // ---------- grouped path: fp16 H throughout ----------
        unsigned short* w = (unsigned short*)p;                 // 12 MiB: 6 mats fp16
        unsigned short* Ah = (unsigned short*)(p + 12 * MiB);   // 40 MiB
        unsigned short* H = (unsigned short*)(p + 52 * MiB);    // 40 MiB (end 92)
        // front: conv(6144 blocks) + l2(5120 blocks)
        k_front<<<6144 + 5120, 256, 0, stream>>>(x, idxs[0], idxs[1], idxs[2],
                                                 Ss[0], Ss[1], Ss[2], Ah, 8192, 16384,
                                                 W1s[0], W2s[0], W1s[1], W2s[1], W1s[2], W2s[2],
                                                 w, 6144);
        dim3 gg(160, 8);
        k_gemm_mfma<1><<<gg, 256, 0, stream>>>(Ah,
            w + 0 * 1048576, w + 2 * 1048576, w + 4 * 1048576,
            b1s[0], b1s[1], b1s[2], H, 64, 128);
        k_ln<<<5120, 256, 0, stream>>>(H, gs[0], gs[1], gs[2], bes[0], bes[1], bes[2],
                                       Ah, 8192, 16384);
        k_gemm_mfma<0><<<gg, 256, 0, stream>>>(Ah,
            w + 1 * 1048576, w + 3 * 1048576, w + 5 * 1048576,
            b2s[0], b2s[1], b2s[2], H, 64, 128);
        k_out<<<5120, 256, 0, stream>>>(x, idxs[0], idxs[1], idxs[2], H, outp, 8192, 16384);
    } else {
        // ---------- per-type fallback ----------
        unsigned short* wt = (unsigned short*)p;  // 4 MiB: W1 fp16 + W2 fp16
        char* dyn = p + 4 * MiB;
        for (int t = 0; t < 3; ++t) {
            int n = NATOMS[t], d = DIMS[t];
            size_t fullneed = 4 * MiB + (size_t)n * 4096;  // A 2KB + H 2KB per atom
            int nch = (ws_size >= fullneed) ? 1 : 2;
            int cm = n / nch;
            unsigned short* Ah = (unsigned short*)dyn;
            unsigned short* Hbuf = (unsigned short*)(dyn + (size_t)cm * 2048);
            int ss1 = (t == 0) ? BIG : 0;
            int ss2 = (t == 2) ? 0 : BIG;
            for (int ch = 0; ch < nch; ++ch) {
                const int* idxc = idxs[t] + (size_t)(ch * cm) * d;
                int nconv = (ch == 0) ? 2048 : 0;  // convert W only on first chunk
                k_front<<<nconv + cm / 4, 256, 0, stream>>>(x, idxc, idxc, idxc,
                                                            Ss[t], Ss[t], Ss[t], Ah, ss1, ss2,
                                                            W1s[t], W2s[t], W1s[t], W1s[t], W1s[t], W1s[t],
                                                            wt, nconv);
                dim3 g1(cm / 128, 8);
                k_gemm_mfma<1><<<g1, 256, 0, stream>>>(Ah,
                    wt + 0, wt + 0, wt + 0,
                    b1s[t], b1s[t], b1s[t], Hbuf, BIG, BIG);
                k_ln<<<cm / 4, 256, 0, stream>>>(Hbuf, gs[t], gs[t], gs[t], bes[t], bes[t], bes[t],
                                                 Ah, ss1, ss2);
                k_gemm_mfma<0><<<g1, 256, 0, stream>>>(Ah,
                    wt + 1048576, wt + 1048576, wt + 1048576,
                    b2s[t], b2s[t], b2s[t], Hbuf, BIG, BIG);
                k_out<<<cm / 4, 256, 0, stream>>>(x, idxc, idxc, idxc, Hbuf, outp, ss1, ss2);
            }
        }
    }
    (void)in_sizes; (void)n_in; (void)out_size;
}